// Round 4
// baseline (529.443 us; speedup 1.0000x reference)
//
#include <hip/hip_runtime.h>
#include <math.h>

typedef unsigned short u16;
typedef __attribute__((ext_vector_type(8))) __bf16 bf16x8v;
typedef __attribute__((ext_vector_type(8))) unsigned short ushort8v;
typedef __attribute__((ext_vector_type(4))) float f32x4v;

#define D_EMBD 1024
#define NHEADS 16
#define DHEAD  64
#define DFF    4096
#define BATCHN 2
#define SEQL   2048
#define TOK    (BATCHN*SEQL)

#define EPI_F32_BIAS_RES 1
#define EPI_BF16_GELU    2
#define EPI_BF16_PLAIN   3
#define EPI_F32_ATOM     4   // split-K: atomicAdd into zeroed f32 out; z==0 adds bias+resid

__device__ __forceinline__ float bf2f(u16 s) {
  return __builtin_bit_cast(float, (unsigned)s << 16);
}
__device__ __forceinline__ u16 f2bf(float f) {
  unsigned u = __builtin_bit_cast(unsigned, f);
  unsigned r = u + 0x7fffu + ((u >> 16) & 1u);
  return (u16)(r >> 16);
}

// async global->LDS, 16B per lane; LDS dest = wave-uniform base + lane*16
#define GLOAD16(gp, lp)                                                        \
  __builtin_amdgcn_global_load_lds(                                            \
      (__attribute__((address_space(1))) void*)(void*)(gp),                    \
      (__attribute__((address_space(3))) void*)(void*)(lp), 16, 0, 0)

__global__ __launch_bounds__(256) void zero_kernel(float4* __restrict__ p, int n4) {
  int i = blockIdx.x * 256 + threadIdx.x;
  float4 z = {0.f, 0.f, 0.f, 0.f};
  if (i < n4) p[i] = z;
}

// f32x4 -> bf16x4 elementwise (weights)
__global__ __launch_bounds__(256) void cvt_kernel(const float* __restrict__ src,
                                                  u16* __restrict__ dst, int n4) {
  int i = blockIdx.x * 256 + threadIdx.x;
  if (i < n4) {
    float4 v = ((const float4*)src)[i];
    ushort4 o;
    o.x = f2bf(v.x); o.y = f2bf(v.y); o.z = f2bf(v.z); o.w = f2bf(v.w);
    ((ushort4*)dst)[i] = o;
  }
}

// LayerNorm over D=1024, one block per row, writes bf16
__global__ __launch_bounds__(256) void ln_kernel(const float* __restrict__ x,
                                                 const float* __restrict__ sc,
                                                 const float* __restrict__ sh,
                                                 u16* __restrict__ out) {
  int row = blockIdx.x, tid = threadIdx.x;
  const float4* xr = (const float4*)(x + (size_t)row * D_EMBD);
  float4 v = xr[tid];
  float s  = (v.x + v.y) + (v.z + v.w);
  float s2 = (v.x * v.x + v.y * v.y) + (v.z * v.z + v.w * v.w);
#pragma unroll
  for (int off = 32; off; off >>= 1) {
    s  += __shfl_xor(s, off, 64);
    s2 += __shfl_xor(s2, off, 64);
  }
  __shared__ float rs[4], rs2[4];
  int wave = tid >> 6, lane = tid & 63;
  if (lane == 0) { rs[wave] = s; rs2[wave] = s2; }
  __syncthreads();
  s  = (rs[0] + rs[1]) + (rs[2] + rs[3]);
  s2 = (rs2[0] + rs2[1]) + (rs2[2] + rs2[3]);
  float mean = s * (1.f / 1024.f);
  float var  = s2 * (1.f / 1024.f) - mean * mean;
  float rstd = rsqrtf(var + 1e-6f);
  float4 scv = ((const float4*)sc)[tid];
  float4 shv = ((const float4*)sh)[tid];
  u16* op = out + (size_t)row * D_EMBD + tid * 4;
  op[0] = f2bf((v.x - mean) * rstd * scv.x + shv.x);
  op[1] = f2bf((v.y - mean) * rstd * scv.y + shv.y);
  op[2] = f2bf((v.z - mean) * rstd * scv.z + shv.z);
  op[3] = f2bf((v.w - mean) * rstd * scv.w + shv.w);
}

// C[M,N] = A[M,K] @ W[N,K]^T, bf16, f32 acc, fused epilogues.
// 128x128 tile, BK=64; global_load_lds width-16 into fragment-order LDS.
// Split-K via blockIdx.z (KC = K/gridDim.z); EPI_F32_ATOM accumulates with
// device-scope atomicAdd into a zero-initialized f32 buffer.
template <int EPI>
__global__ __launch_bounds__(256) void gemm_nt(const u16* __restrict__ A,
                                               const u16* __restrict__ W,
                                               float* __restrict__ Cf,
                                               u16* __restrict__ Cb,
                                               const float* __restrict__ bias,
                                               const float* __restrict__ resid,
                                               int M, int N, int K) {
  __shared__ u16 As[8192];  // 16 KB
  __shared__ u16 Ws[8192];
  int tid = threadIdx.x;
  int wave = tid >> 6, lane = tid & 63;
  int wm = wave >> 1, wn = wave & 1;
  int lr = lane & 15, quad = lane >> 4;
  int m0 = blockIdx.y * 128, n0 = blockIdx.x * 128;
  int KC = K / gridDim.z;
  int kbeg = blockIdx.z * KC, kend = kbeg + KC;

  f32x4v acc[4][4];
#pragma unroll
  for (int i = 0; i < 4; i++)
#pragma unroll
    for (int j = 0; j < 4; j++) {
      f32x4v z = {0.f, 0.f, 0.f, 0.f};
      acc[i][j] = z;
    }

  for (int k0 = kbeg; k0 < kend; k0 += 64) {
#pragma unroll
    for (int p = 0; p < 4; ++p) {
      int q = wave * 4 + p;                 // 0..15: rowblk=q>>1, kkblk=q&1
      int row = ((q >> 1) << 4) + lr;
      int col = k0 + (((q & 1) << 2) + quad) * 8;
      GLOAD16(A + (size_t)(m0 + row) * K + col, (char*)As + q * 1024);
      GLOAD16(W + (size_t)(n0 + row) * K + col, (char*)Ws + q * 1024);
    }
    __syncthreads();   // drains vmcnt -> LDS tiles ready
    const bf16x8v* As4 = (const bf16x8v*)As;
    const bf16x8v* Ws4 = (const bf16x8v*)Ws;
#pragma unroll
    for (int kk = 0; kk < 2; ++kk) {
      bf16x8v af[4], bw[4];
#pragma unroll
      for (int i = 0; i < 4; i++) af[i] = As4[(((wm * 4 + i) * 2 + kk) << 6) + lane];
#pragma unroll
      for (int j = 0; j < 4; j++) bw[j] = Ws4[(((wn * 4 + j) * 2 + kk) << 6) + lane];
#pragma unroll
      for (int i = 0; i < 4; i++)
#pragma unroll
        for (int j = 0; j < 4; j++)
          acc[i][j] = __builtin_amdgcn_mfma_f32_16x16x32_bf16(af[i], bw[j], acc[i][j], 0, 0, 0);
    }
    __syncthreads();   // protect LDS before next iter's staging
  }

#pragma unroll
  for (int i = 0; i < 4; i++) {
#pragma unroll
    for (int j = 0; j < 4; j++) {
#pragma unroll
      for (int r = 0; r < 4; r++) {
        int gr = m0 + wm * 64 + i * 16 + quad * 4 + r;
        int gc = n0 + wn * 64 + j * 16 + lr;
        size_t idx = (size_t)gr * N + gc;
        float v = acc[i][j][r];
        if constexpr (EPI == EPI_F32_BIAS_RES) {
          Cf[idx] = v + bias[gc] + resid[idx];
        } else if constexpr (EPI == EPI_F32_ATOM) {
          if (blockIdx.z == 0) v += bias[gc] + resid[idx];
          atomicAdd(&Cf[idx], v);
        } else if constexpr (EPI == EPI_BF16_PLAIN) {
          Cb[idx] = f2bf(v);
        } else {
          v += bias[gc];
          float z = 0.7978845608028654f * (v + 0.044715f * v * v * v);
          float t = 2.f / (1.f + __expf(-2.f * z)) - 1.f;
          Cb[idx] = f2bf(0.5f * v * (1.f + t));
        }
      }
    }
  }
}

// ---------------- MFMA flash attention (causal) ----------------
#define VTS 72
__device__ __forceinline__ void stage_k(const u16* Kbase, int ks, u16* kfbuf,
                                        int wave, int lr, int quad) {
#pragma unroll
  for (int p = 0; p < 2; ++p) {
    int q = wave * 2 + p;
    int key = ((q >> 1) << 4) + lr;
    int c8 = ((q & 1) << 2) + quad;
    GLOAD16(Kbase + (size_t)(ks + key) * 3072 + c8 * 8, (char*)kfbuf + q * 1024);
  }
}
__device__ __forceinline__ void load_v(const u16* Vbase, int ks, int vkey0, int vc8,
                                       ushort8v& va, ushort8v& vb) {
  va = *(const ushort8v*)(Vbase + (size_t)(ks + vkey0) * 3072 + vc8 * 8);
  vb = *(const ushort8v*)(Vbase + (size_t)(ks + vkey0 + 1) * 3072 + vc8 * 8);
}
__device__ __forceinline__ void write_vt(u16* vt, int vc8, int vcol,
                                         ushort8v va, ushort8v vb) {
#pragma unroll
  for (int j = 0; j < 8; ++j) {
    unsigned pk = (unsigned)va[j] | ((unsigned)vb[j] << 16);
    *(unsigned*)(vt + (size_t)(vc8 * 8 + j) * VTS + vcol) = pk;
  }
}

__global__ __launch_bounds__(256) void attn_kernel(const u16* __restrict__ qkv,
                                                   u16* __restrict__ ctx) {
  __shared__ u16 Kf[2][4096];
  __shared__ u16 Vt[2][64 * VTS];
  __shared__ u16 Ps[4 * 16 * VTS];
  int tid = threadIdx.x;
  int wave = tid >> 6, lane = tid & 63;
  int lr = lane & 15, quad = lane >> 4;
  int id = blockIdx.x;
  int bh = id & 31;
  int k5 = id >> 5, gg = k5 >> 3, jj = k5 & 7;
  int t = (gg == 0) ? jj : (gg == 1) ? 15 - jj : (gg == 2) ? 16 + jj : 31 - jj;
  int b = bh >> 4, h = bh & 15;
  int q0 = t * 64;
  const u16* qkvb = qkv + (size_t)(b * SEQL) * 3072;
  int qrow = q0 + wave * 16 + lr;
  const u16* Qp = qkvb + (size_t)qrow * 3072 + h * 64 + quad * 8;
  bf16x8v qf0 = *(const bf16x8v*)(Qp);
  bf16x8v qf1 = *(const bf16x8v*)(Qp + 32);
  const u16* Kbase = qkvb + 1024 + h * 64;
  const u16* Vbase = qkvb + 2048 + h * 64;
  int vkey0 = (tid >> 3) * 2, vc8 = tid & 7;
  int vcol = (((vkey0 >> 3) ^ vc8) << 3) + (vkey0 & 7);

  float mrow[4], lrow[4];
  f32x4v accO[4];
#pragma unroll
  for (int r = 0; r < 4; r++) {
    mrow[r] = -INFINITY;
    lrow[r] = 0.f;
    f32x4v z = {0.f, 0.f, 0.f, 0.f};
    accO[r] = z;
  }

  int nkt = t + 1;
  {
    stage_k(Kbase, 0, Kf[0], wave, lr, quad);
    ushort8v va, vb;
    load_v(Vbase, 0, vkey0, vc8, va, vb);
    write_vt(Vt[0], vc8, vcol, va, vb);
  }
  __syncthreads();

  for (int kt = 0; kt < nkt; ++kt) {
    int cur = kt & 1, nxt = cur ^ 1;
    ushort8v va, vb;
    bool pre = (kt + 1 < nkt);
    if (pre) {
      stage_k(Kbase, (kt + 1) * 64, Kf[nxt], wave, lr, quad);
      load_v(Vbase, (kt + 1) * 64, vkey0, vc8, va, vb);
    }
    const bf16x8v* Kc = (const bf16x8v*)Kf[cur];
    const u16* Vc = Vt[cur];
    f32x4v accS[4];
#pragma unroll
    for (int jb = 0; jb < 4; jb++) {
      f32x4v z = {0.f, 0.f, 0.f, 0.f};
      accS[jb] = z;
    }
#pragma unroll
    for (int jb = 0; jb < 4; jb++) {
      accS[jb] = __builtin_amdgcn_mfma_f32_16x16x32_bf16(qf0, Kc[((jb * 2 + 0) << 6) + lane], accS[jb], 0, 0, 0);
      accS[jb] = __builtin_amdgcn_mfma_f32_16x16x32_bf16(qf1, Kc[((jb * 2 + 1) << 6) + lane], accS[jb], 0, 0, 0);
    }
    if (kt == t) {
#pragma unroll
      for (int jb = 0; jb < 4; jb++)
#pragma unroll
        for (int r = 0; r < 4; r++) {
          int keyg = jb * 16 + lr;
          int rowg = wave * 16 + quad * 4 + r;
          if (keyg > rowg) accS[jb][r] = -INFINITY;
        }
    }
    float mx[4], al[4], psum[4];
#pragma unroll
    for (int r = 0; r < 4; r++)
      mx[r] = fmaxf(fmaxf(accS[0][r], accS[1][r]), fmaxf(accS[2][r], accS[3][r]));
#pragma unroll
    for (int off = 8; off; off >>= 1)
#pragma unroll
      for (int r = 0; r < 4; r++) mx[r] = fmaxf(mx[r], __shfl_xor(mx[r], off, 64));
#pragma unroll
    for (int r = 0; r < 4; r++) {
      float mn = fmaxf(mrow[r], mx[r]);
      al[r] = __expf((mrow[r] - mn) * 0.125f);
      mrow[r] = mn;
    }
#pragma unroll
    for (int jb = 0; jb < 4; jb++)
#pragma unroll
      for (int r = 0; r < 4; r++)
        accS[jb][r] = __expf((accS[jb][r] - mrow[r]) * 0.125f);
#pragma unroll
    for (int r = 0; r < 4; r++)
      psum[r] = (accS[0][r] + accS[1][r]) + (accS[2][r] + accS[3][r]);
#pragma unroll
    for (int off = 8; off; off >>= 1)
#pragma unroll
      for (int r = 0; r < 4; r++) psum[r] += __shfl_xor(psum[r], off, 64);
#pragma unroll
    for (int r = 0; r < 4; r++) lrow[r] = lrow[r] * al[r] + psum[r];
#pragma unroll
    for (int nb = 0; nb < 4; nb++)
#pragma unroll
      for (int r = 0; r < 4; r++) accO[nb][r] *= al[r];
    u16* myP = Ps + wave * 16 * VTS;
#pragma unroll
    for (int jb = 0; jb < 4; jb++)
#pragma unroll
      for (int r = 0; r < 4; r++)
        myP[(quad * 4 + r) * VTS + jb * 16 + lr] = f2bf(accS[jb][r]);
#pragma unroll
    for (int kk = 0; kk < 2; ++kk) {
      bf16x8v pa = *(const bf16x8v*)(myP + lr * VTS + quad * 8 + kk * 32);
#pragma unroll
      for (int nb = 0; nb < 4; nb++) {
        int dim = nb * 16 + lr;
        int f = (dim >> 3) & 7;
        bf16x8v vfr = *(const bf16x8v*)(Vc + dim * VTS + (((quad + 4 * kk) ^ f) << 3));
        accO[nb] = __builtin_amdgcn_mfma_f32_16x16x32_bf16(pa, vfr, accO[nb], 0, 0, 0);
      }
    }
    if (pre) write_vt(Vt[nxt], vc8, vcol, va, vb);
    __syncthreads();
  }
  float rinv[4];
#pragma unroll
  for (int r = 0; r < 4; r++) rinv[r] = 1.f / lrow[r];
#pragma unroll
  for (int nb = 0; nb < 4; nb++)
#pragma unroll
    for (int r = 0; r < 4; r++) {
      int rowg = q0 + wave * 16 + quad * 4 + r;
      ctx[(size_t)(b * SEQL + rowg) * D_EMBD + h * 64 + nb * 16 + lr] =
          f2bf(accO[nb][r] * rinv[r]);
    }
}

extern "C" void kernel_launch(void* const* d_in, const int* in_sizes, int n_in,
                              void* d_out, int out_size, void* d_ws, size_t ws_size,
                              hipStream_t stream) {
  const float* x    = (const float*)d_in[0];
  const float* wq   = (const float*)d_in[1];
  const float* wk   = (const float*)d_in[2];
  const float* wv   = (const float*)d_in[3];
  const float* wo   = (const float*)d_in[4];
  const float* bo   = (const float*)d_in[5];
  const float* w1   = (const float*)d_in[6];
  const float* b1   = (const float*)d_in[7];
  const float* w2   = (const float*)d_in[8];
  const float* b2   = (const float*)d_in[9];
  const float* ln1s = (const float*)d_in[10];
  const float* ln1b = (const float*)d_in[11];
  const float* ln2s = (const float*)d_in[12];
  const float* ln2b = (const float*)d_in[13];
  float* out = (float*)d_out;

  char* base = (char*)d_ws;
  size_t off = 0;
  auto alloc = [&](size_t bytes) {
    char* r = base + off;
    off += (bytes + 255) & ~(size_t)255;
    return r;
  };
  u16*   wcat = (u16*)alloc((size_t)3072 * 1024 * 2);
  u16*   wob  = (u16*)alloc((size_t)1024 * 1024 * 2);
  u16*   w1b  = (u16*)alloc((size_t)4096 * 1024 * 2);
  u16*   w2b  = (u16*)alloc((size_t)1024 * 4096 * 2);
  u16*   xn   = (u16*)alloc((size_t)TOK * 1024 * 2);
  u16*   qkv  = (u16*)alloc((size_t)TOK * 3072 * 2);
  u16*   ctx  = (u16*)alloc((size_t)TOK * 1024 * 2);
  float* hbuf = (float*)alloc((size_t)TOK * 1024 * 4);
  u16*   ybuf = (u16*)alloc((size_t)TOK * 1024 * 2);
  u16*   gbuf = (u16*)alloc((size_t)TOK * 4096 * 2);

  // zero split-K accumulators (hbuf, out): 1M float4 each
  zero_kernel<<<4096, 256, 0, stream>>>((float4*)hbuf, 1024 * 1024);
  zero_kernel<<<4096, 256, 0, stream>>>((float4*)out, 1024 * 1024);

  cvt_kernel<<<1024, 256, 0, stream>>>(wq, wcat, 256 * 1024);
  cvt_kernel<<<1024, 256, 0, stream>>>(wk, wcat + 1024 * 1024, 256 * 1024);
  cvt_kernel<<<1024, 256, 0, stream>>>(wv, wcat + 2 * 1024 * 1024, 256 * 1024);
  cvt_kernel<<<1024, 256, 0, stream>>>(wo, wob, 256 * 1024);
  cvt_kernel<<<4096, 256, 0, stream>>>(w1, w1b, 1024 * 1024);
  cvt_kernel<<<4096, 256, 0, stream>>>(w2, w2b, 1024 * 1024);

  ln_kernel<<<TOK, 256, 0, stream>>>(x, ln1s, ln1b, xn);
  gemm_nt<EPI_BF16_PLAIN><<<dim3(24, 32), 256, 0, stream>>>(
      xn, wcat, nullptr, qkv, nullptr, nullptr, TOK, 3072, 1024);
  attn_kernel<<<1024, 256, 0, stream>>>(qkv, ctx);
  // h = x + ctx @ wo^T + bo   (split-K=2, atomic accumulate)
  gemm_nt<EPI_F32_ATOM><<<dim3(8, 32, 2), 256, 0, stream>>>(
      ctx, wob, hbuf, nullptr, bo, x, TOK, 1024, 1024);
  ln_kernel<<<TOK, 256, 0, stream>>>(hbuf, ln2s, ln2b, ybuf);
  gemm_nt<EPI_BF16_GELU><<<dim3(32, 32), 256, 0, stream>>>(
      ybuf, w1b, nullptr, gbuf, b1, nullptr, TOK, 4096, 1024);
  // out = h + g @ w2^T + b2   (split-K=4, atomic accumulate)
  gemm_nt<EPI_F32_ATOM><<<dim3(8, 32, 4), 256, 0, stream>>>(
      gbuf, w2b, out, nullptr, b2, hbuf, TOK, 1024, 4096);
}

// Round 5
// 465.766 us; speedup vs baseline: 1.1367x; 1.1367x over previous
//
#include <hip/hip_runtime.h>
#include <math.h>

typedef unsigned short u16;
typedef __attribute__((ext_vector_type(8))) __bf16 bf16x8v;
typedef __attribute__((ext_vector_type(8))) unsigned short ushort8v;
typedef __attribute__((ext_vector_type(4))) float f32x4v;

#define D_EMBD 1024
#define NHEADS 16
#define DHEAD  64
#define DFF    4096
#define BATCHN 2
#define SEQL   2048
#define TOK    (BATCHN*SEQL)

#define EPI_F32_BIAS_RES 1
#define EPI_BF16_GELU    2
#define EPI_BF16_PLAIN   3
#define EPI_F32_PART     4   // split-K: f32 partial at Cf + z*M*N
#define EPI_BF16_PART    5   // split-K: bf16 partial at Cb + z*M*N

__device__ __forceinline__ float bf2f(u16 s) {
  return __builtin_bit_cast(float, (unsigned)s << 16);
}
__device__ __forceinline__ u16 f2bf(float f) {
  unsigned u = __builtin_bit_cast(unsigned, f);
  unsigned r = u + 0x7fffu + ((u >> 16) & 1u);
  return (u16)(r >> 16);
}

// async global->LDS, 16B per lane; LDS dest = wave-uniform base + lane*16
#define GLOAD16(gp, lp)                                                        \
  __builtin_amdgcn_global_load_lds(                                            \
      (__attribute__((address_space(1))) void*)(void*)(gp),                    \
      (__attribute__((address_space(3))) void*)(void*)(lp), 16, 0, 0)

// f32x4 -> bf16x4 elementwise (weights)
__global__ __launch_bounds__(256) void cvt_kernel(const float* __restrict__ src,
                                                  u16* __restrict__ dst, int n4) {
  int i = blockIdx.x * 256 + threadIdx.x;
  if (i < n4) {
    float4 v = ((const float4*)src)[i];
    ushort4 o;
    o.x = f2bf(v.x); o.y = f2bf(v.y); o.z = f2bf(v.z); o.w = f2bf(v.w);
    ((ushort4*)dst)[i] = o;
  }
}

// LayerNorm over D=1024, one block per row, writes bf16
__global__ __launch_bounds__(256) void ln_kernel(const float* __restrict__ x,
                                                 const float* __restrict__ sc,
                                                 const float* __restrict__ sh,
                                                 u16* __restrict__ out) {
  int row = blockIdx.x, tid = threadIdx.x;
  const float4* xr = (const float4*)(x + (size_t)row * D_EMBD);
  float4 v = xr[tid];
  float s  = (v.x + v.y) + (v.z + v.w);
  float s2 = (v.x * v.x + v.y * v.y) + (v.z * v.z + v.w * v.w);
#pragma unroll
  for (int off = 32; off; off >>= 1) {
    s  += __shfl_xor(s, off, 64);
    s2 += __shfl_xor(s2, off, 64);
  }
  __shared__ float rs[4], rs2[4];
  int wave = tid >> 6, lane = tid & 63;
  if (lane == 0) { rs[wave] = s; rs2[wave] = s2; }
  __syncthreads();
  s  = (rs[0] + rs[1]) + (rs[2] + rs[3]);
  s2 = (rs2[0] + rs2[1]) + (rs2[2] + rs2[3]);
  float mean = s * (1.f / 1024.f);
  float var  = s2 * (1.f / 1024.f) - mean * mean;
  float rstd = rsqrtf(var + 1e-6f);
  float4 scv = ((const float4*)sc)[tid];
  float4 shv = ((const float4*)sh)[tid];
  u16* op = out + (size_t)row * D_EMBD + tid * 4;
  op[0] = f2bf((v.x - mean) * rstd * scv.x + shv.x);
  op[1] = f2bf((v.y - mean) * rstd * scv.y + shv.y);
  op[2] = f2bf((v.z - mean) * rstd * scv.z + shv.z);
  op[3] = f2bf((v.w - mean) * rstd * scv.w + shv.w);
}

// split-K reduce for wo: h = p0 + p1 + bias + resid   (f32 partials, N=1024)
__global__ __launch_bounds__(256) void reduce_wo_kernel(const float* __restrict__ parts,
                                                        const float* __restrict__ resid,
                                                        const float* __restrict__ bias,
                                                        float* __restrict__ out) {
  int i = blockIdx.x * 256 + threadIdx.x;   // float4 index, 1M total
  const float4* p0 = (const float4*)parts;
  const float4* p1 = p0 + (1 << 20);
  float4 a = p0[i], b = p1[i];
  float4 r = ((const float4*)resid)[i];
  float4 bi = ((const float4*)bias)[i & 255];
  float4 o;
  o.x = a.x + b.x + r.x + bi.x;
  o.y = a.y + b.y + r.y + bi.y;
  o.z = a.z + b.z + r.z + bi.z;
  o.w = a.w + b.w + r.w + bi.w;
  ((float4*)out)[i] = o;
}

// split-K reduce for w2: out = sum_{4} bf16 partials + bias + resid
__global__ __launch_bounds__(256) void reduce_w2_kernel(const u16* __restrict__ parts,
                                                        const float* __restrict__ resid,
                                                        const float* __restrict__ bias,
                                                        float* __restrict__ out) {
  int i = blockIdx.x * 256 + threadIdx.x;   // 4-elem group index, 1M total
  float4 r = ((const float4*)resid)[i];
  float4 bi = ((const float4*)bias)[i & 255];
  float s0 = 0, s1 = 0, s2 = 0, s3 = 0;
#pragma unroll
  for (int p = 0; p < 4; ++p) {
    ushort4 u = ((const ushort4*)(parts + (size_t)p * 4194304))[i];
    s0 += bf2f(u.x); s1 += bf2f(u.y); s2 += bf2f(u.z); s3 += bf2f(u.w);
  }
  float4 o = {s0 + r.x + bi.x, s1 + r.y + bi.y, s2 + r.z + bi.z, s3 + r.w + bi.w};
  ((float4*)out)[i] = o;
}

// C[M,N] = A[M,K] @ W[N,K]^T, bf16, f32 acc, fused epilogues.
// 128x128 tile, BK=64; global_load_lds width-16 into fragment-order LDS.
// Split-K via blockIdx.z (KC = K/gridDim.z) writing partial buffers.
template <int EPI>
__global__ __launch_bounds__(256) void gemm_nt(const u16* __restrict__ A,
                                               const u16* __restrict__ W,
                                               float* __restrict__ Cf,
                                               u16* __restrict__ Cb,
                                               const float* __restrict__ bias,
                                               const float* __restrict__ resid,
                                               int M, int N, int K) {
  __shared__ u16 As[8192];  // 16 KB
  __shared__ u16 Ws[8192];
  int tid = threadIdx.x;
  int wave = tid >> 6, lane = tid & 63;
  int wm = wave >> 1, wn = wave & 1;
  int lr = lane & 15, quad = lane >> 4;
  int m0 = blockIdx.y * 128, n0 = blockIdx.x * 128;
  int KC = K / gridDim.z;
  int kbeg = blockIdx.z * KC, kend = kbeg + KC;
  size_t poff = (size_t)blockIdx.z * M * N;

  f32x4v acc[4][4];
#pragma unroll
  for (int i = 0; i < 4; i++)
#pragma unroll
    for (int j = 0; j < 4; j++) {
      f32x4v z = {0.f, 0.f, 0.f, 0.f};
      acc[i][j] = z;
    }

  for (int k0 = kbeg; k0 < kend; k0 += 64) {
#pragma unroll
    for (int p = 0; p < 4; ++p) {
      int q = wave * 4 + p;                 // 0..15: rowblk=q>>1, kkblk=q&1
      int row = ((q >> 1) << 4) + lr;
      int col = k0 + (((q & 1) << 2) + quad) * 8;
      GLOAD16(A + (size_t)(m0 + row) * K + col, (char*)As + q * 1024);
      GLOAD16(W + (size_t)(n0 + row) * K + col, (char*)Ws + q * 1024);
    }
    __syncthreads();   // drains vmcnt -> LDS tiles ready
    const bf16x8v* As4 = (const bf16x8v*)As;
    const bf16x8v* Ws4 = (const bf16x8v*)Ws;
#pragma unroll
    for (int kk = 0; kk < 2; ++kk) {
      bf16x8v af[4], bw[4];
#pragma unroll
      for (int i = 0; i < 4; i++) af[i] = As4[(((wm * 4 + i) * 2 + kk) << 6) + lane];
#pragma unroll
      for (int j = 0; j < 4; j++) bw[j] = Ws4[(((wn * 4 + j) * 2 + kk) << 6) + lane];
#pragma unroll
      for (int i = 0; i < 4; i++)
#pragma unroll
        for (int j = 0; j < 4; j++)
          acc[i][j] = __builtin_amdgcn_mfma_f32_16x16x32_bf16(af[i], bw[j], acc[i][j], 0, 0, 0);
    }
    __syncthreads();   // protect LDS before next iter's staging
  }

#pragma unroll
  for (int i = 0; i < 4; i++) {
#pragma unroll
    for (int j = 0; j < 4; j++) {
#pragma unroll
      for (int r = 0; r < 4; r++) {
        int gr = m0 + wm * 64 + i * 16 + quad * 4 + r;
        int gc = n0 + wn * 64 + j * 16 + lr;
        size_t idx = (size_t)gr * N + gc;
        float v = acc[i][j][r];
        if constexpr (EPI == EPI_F32_BIAS_RES) {
          Cf[idx] = v + bias[gc] + resid[idx];
        } else if constexpr (EPI == EPI_F32_PART) {
          Cf[poff + idx] = v;
        } else if constexpr (EPI == EPI_BF16_PART) {
          Cb[poff + idx] = f2bf(v);
        } else if constexpr (EPI == EPI_BF16_PLAIN) {
          Cb[idx] = f2bf(v);
        } else {
          v += bias[gc];
          float z = 0.7978845608028654f * (v + 0.044715f * v * v * v);
          float t = 2.f / (1.f + __expf(-2.f * z)) - 1.f;
          Cb[idx] = f2bf(0.5f * v * (1.f + t));
        }
      }
    }
  }
}

// ---------------- MFMA flash attention (causal) ----------------
#define VTS 72
__device__ __forceinline__ void stage_k(const u16* Kbase, int ks, u16* kfbuf,
                                        int wave, int lr, int quad) {
#pragma unroll
  for (int p = 0; p < 2; ++p) {
    int q = wave * 2 + p;
    int key = ((q >> 1) << 4) + lr;
    int c8 = ((q & 1) << 2) + quad;
    GLOAD16(Kbase + (size_t)(ks + key) * 3072 + c8 * 8, (char*)kfbuf + q * 1024);
  }
}
__device__ __forceinline__ void load_v(const u16* Vbase, int ks, int vkey0, int vc8,
                                       ushort8v& va, ushort8v& vb) {
  va = *(const ushort8v*)(Vbase + (size_t)(ks + vkey0) * 3072 + vc8 * 8);
  vb = *(const ushort8v*)(Vbase + (size_t)(ks + vkey0 + 1) * 3072 + vc8 * 8);
}
__device__ __forceinline__ void write_vt(u16* vt, int vc8, int vcol,
                                         ushort8v va, ushort8v vb) {
#pragma unroll
  for (int j = 0; j < 8; ++j) {
    unsigned pk = (unsigned)va[j] | ((unsigned)vb[j] << 16);
    *(unsigned*)(vt + (size_t)(vc8 * 8 + j) * VTS + vcol) = pk;
  }
}

__global__ __launch_bounds__(256) void attn_kernel(const u16* __restrict__ qkv,
                                                   u16* __restrict__ ctx) {
  __shared__ u16 Kf[2][4096];
  __shared__ u16 Vt[2][64 * VTS];
  __shared__ u16 Ps[4 * 16 * VTS];
  int tid = threadIdx.x;
  int wave = tid >> 6, lane = tid & 63;
  int lr = lane & 15, quad = lane >> 4;
  int id = blockIdx.x;
  int bh = id & 31;
  int k5 = id >> 5, gg = k5 >> 3, jj = k5 & 7;
  int t = (gg == 0) ? jj : (gg == 1) ? 15 - jj : (gg == 2) ? 16 + jj : 31 - jj;
  int b = bh >> 4, h = bh & 15;
  int q0 = t * 64;
  const u16* qkvb = qkv + (size_t)(b * SEQL) * 3072;
  int qrow = q0 + wave * 16 + lr;
  const u16* Qp = qkvb + (size_t)qrow * 3072 + h * 64 + quad * 8;
  bf16x8v qf0 = *(const bf16x8v*)(Qp);
  bf16x8v qf1 = *(const bf16x8v*)(Qp + 32);
  const u16* Kbase = qkvb + 1024 + h * 64;
  const u16* Vbase = qkvb + 2048 + h * 64;
  int vkey0 = (tid >> 3) * 2, vc8 = tid & 7;
  int vcol = (((vkey0 >> 3) ^ vc8) << 3) + (vkey0 & 7);

  float mrow[4], lrow[4];
  f32x4v accO[4];
#pragma unroll
  for (int r = 0; r < 4; r++) {
    mrow[r] = -INFINITY;
    lrow[r] = 0.f;
    f32x4v z = {0.f, 0.f, 0.f, 0.f};
    accO[r] = z;
  }

  int nkt = t + 1;
  {
    stage_k(Kbase, 0, Kf[0], wave, lr, quad);
    ushort8v va, vb;
    load_v(Vbase, 0, vkey0, vc8, va, vb);
    write_vt(Vt[0], vc8, vcol, va, vb);
  }
  __syncthreads();

  for (int kt = 0; kt < nkt; ++kt) {
    int cur = kt & 1, nxt = cur ^ 1;
    ushort8v va, vb;
    bool pre = (kt + 1 < nkt);
    if (pre) {
      stage_k(Kbase, (kt + 1) * 64, Kf[nxt], wave, lr, quad);
      load_v(Vbase, (kt + 1) * 64, vkey0, vc8, va, vb);
    }
    const bf16x8v* Kc = (const bf16x8v*)Kf[cur];
    const u16* Vc = Vt[cur];
    f32x4v accS[4];
#pragma unroll
    for (int jb = 0; jb < 4; jb++) {
      f32x4v z = {0.f, 0.f, 0.f, 0.f};
      accS[jb] = z;
    }
#pragma unroll
    for (int jb = 0; jb < 4; jb++) {
      accS[jb] = __builtin_amdgcn_mfma_f32_16x16x32_bf16(qf0, Kc[((jb * 2 + 0) << 6) + lane], accS[jb], 0, 0, 0);
      accS[jb] = __builtin_amdgcn_mfma_f32_16x16x32_bf16(qf1, Kc[((jb * 2 + 1) << 6) + lane], accS[jb], 0, 0, 0);
    }
    if (kt == t) {
#pragma unroll
      for (int jb = 0; jb < 4; jb++)
#pragma unroll
        for (int r = 0; r < 4; r++) {
          int keyg = jb * 16 + lr;
          int rowg = wave * 16 + quad * 4 + r;
          if (keyg > rowg) accS[jb][r] = -INFINITY;
        }
    }
    float mx[4], al[4], psum[4];
#pragma unroll
    for (int r = 0; r < 4; r++)
      mx[r] = fmaxf(fmaxf(accS[0][r], accS[1][r]), fmaxf(accS[2][r], accS[3][r]));
#pragma unroll
    for (int off = 8; off; off >>= 1)
#pragma unroll
      for (int r = 0; r < 4; r++) mx[r] = fmaxf(mx[r], __shfl_xor(mx[r], off, 64));
#pragma unroll
    for (int r = 0; r < 4; r++) {
      float mn = fmaxf(mrow[r], mx[r]);
      al[r] = __expf((mrow[r] - mn) * 0.125f);
      mrow[r] = mn;
    }
#pragma unroll
    for (int jb = 0; jb < 4; jb++)
#pragma unroll
      for (int r = 0; r < 4; r++)
        accS[jb][r] = __expf((accS[jb][r] - mrow[r]) * 0.125f);
#pragma unroll
    for (int r = 0; r < 4; r++)
      psum[r] = (accS[0][r] + accS[1][r]) + (accS[2][r] + accS[3][r]);
#pragma unroll
    for (int off = 8; off; off >>= 1)
#pragma unroll
      for (int r = 0; r < 4; r++) psum[r] += __shfl_xor(psum[r], off, 64);
#pragma unroll
    for (int r = 0; r < 4; r++) lrow[r] = lrow[r] * al[r] + psum[r];
#pragma unroll
    for (int nb = 0; nb < 4; nb++)
#pragma unroll
      for (int r = 0; r < 4; r++) accO[nb][r] *= al[r];
    u16* myP = Ps + wave * 16 * VTS;
#pragma unroll
    for (int jb = 0; jb < 4; jb++)
#pragma unroll
      for (int r = 0; r < 4; r++)
        myP[(quad * 4 + r) * VTS + jb * 16 + lr] = f2bf(accS[jb][r]);
#pragma unroll
    for (int kk = 0; kk < 2; ++kk) {
      bf16x8v pa = *(const bf16x8v*)(myP + lr * VTS + quad * 8 + kk * 32);
#pragma unroll
      for (int nb = 0; nb < 4; nb++) {
        int dim = nb * 16 + lr;
        int f = (dim >> 3) & 7;
        bf16x8v vfr = *(const bf16x8v*)(Vc + dim * VTS + (((quad + 4 * kk) ^ f) << 3));
        accO[nb] = __builtin_amdgcn_mfma_f32_16x16x32_bf16(pa, vfr, accO[nb], 0, 0, 0);
      }
    }
    if (pre) write_vt(Vt[nxt], vc8, vcol, va, vb);
    __syncthreads();
  }
  float rinv[4];
#pragma unroll
  for (int r = 0; r < 4; r++) rinv[r] = 1.f / lrow[r];
#pragma unroll
  for (int nb = 0; nb < 4; nb++)
#pragma unroll
    for (int r = 0; r < 4; r++) {
      int rowg = q0 + wave * 16 + quad * 4 + r;
      ctx[(size_t)(b * SEQL + rowg) * D_EMBD + h * 64 + nb * 16 + lr] =
          f2bf(accO[nb][r] * rinv[r]);
    }
}

extern "C" void kernel_launch(void* const* d_in, const int* in_sizes, int n_in,
                              void* d_out, int out_size, void* d_ws, size_t ws_size,
                              hipStream_t stream) {
  const float* x    = (const float*)d_in[0];
  const float* wq   = (const float*)d_in[1];
  const float* wk   = (const float*)d_in[2];
  const float* wv   = (const float*)d_in[3];
  const float* wo   = (const float*)d_in[4];
  const float* bo   = (const float*)d_in[5];
  const float* w1   = (const float*)d_in[6];
  const float* b1   = (const float*)d_in[7];
  const float* w2   = (const float*)d_in[8];
  const float* b2   = (const float*)d_in[9];
  const float* ln1s = (const float*)d_in[10];
  const float* ln1b = (const float*)d_in[11];
  const float* ln2s = (const float*)d_in[12];
  const float* ln2b = (const float*)d_in[13];
  float* out = (float*)d_out;

  char* base = (char*)d_ws;
  size_t off = 0;
  auto alloc = [&](size_t bytes) {
    char* r = base + off;
    off += (bytes + 255) & ~(size_t)255;
    return r;
  };
  u16*   wcat = (u16*)alloc((size_t)3072 * 1024 * 2);
  u16*   wob  = (u16*)alloc((size_t)1024 * 1024 * 2);
  u16*   w1b  = (u16*)alloc((size_t)4096 * 1024 * 2);
  u16*   w2b  = (u16*)alloc((size_t)1024 * 4096 * 2);
  u16*   xn   = (u16*)alloc((size_t)TOK * 1024 * 2);   // 8 MB
  u16*   qkv  = (u16*)alloc((size_t)TOK * 3072 * 2);   // 24 MB (xn+qkv = 32 MB)
  u16*   ctx  = (u16*)alloc((size_t)TOK * 1024 * 2);
  float* hbuf = (float*)alloc((size_t)TOK * 1024 * 4);
  u16*   ybuf = (u16*)alloc((size_t)TOK * 1024 * 2);
  u16*   gbuf = (u16*)alloc((size_t)TOK * 4096 * 2);
  // split-K partials OVERLAY the dead xn+qkv region (32 MB):
  //   wo partials: 2 x 4M f32 (written after attn consumed qkv)
  //   w2 partials: 4 x 4M bf16 (written after wo reduce consumed wo partials)
  float* woP = (float*)xn;
  u16*   w2P = (u16*)xn;

  cvt_kernel<<<1024, 256, 0, stream>>>(wq, wcat, 256 * 1024);
  cvt_kernel<<<1024, 256, 0, stream>>>(wk, wcat + 1024 * 1024, 256 * 1024);
  cvt_kernel<<<1024, 256, 0, stream>>>(wv, wcat + 2 * 1024 * 1024, 256 * 1024);
  cvt_kernel<<<1024, 256, 0, stream>>>(wo, wob, 256 * 1024);
  cvt_kernel<<<4096, 256, 0, stream>>>(w1, w1b, 1024 * 1024);
  cvt_kernel<<<4096, 256, 0, stream>>>(w2, w2b, 1024 * 1024);

  ln_kernel<<<TOK, 256, 0, stream>>>(x, ln1s, ln1b, xn);
  gemm_nt<EPI_BF16_PLAIN><<<dim3(24, 32), 256, 0, stream>>>(
      xn, wcat, nullptr, qkv, nullptr, nullptr, TOK, 3072, 1024);
  attn_kernel<<<1024, 256, 0, stream>>>(qkv, ctx);
  // h = x + ctx @ wo^T + bo   (split-K=2 -> f32 partials -> reduce)
  gemm_nt<EPI_F32_PART><<<dim3(8, 32, 2), 256, 0, stream>>>(
      ctx, wob, woP, nullptr, nullptr, nullptr, TOK, 1024, 1024);
  reduce_wo_kernel<<<4096, 256, 0, stream>>>(woP, x, bo, hbuf);
  ln_kernel<<<TOK, 256, 0, stream>>>(hbuf, ln2s, ln2b, ybuf);
  gemm_nt<EPI_BF16_GELU><<<dim3(32, 32), 256, 0, stream>>>(
      ybuf, w1b, nullptr, gbuf, b1, nullptr, TOK, 4096, 1024);
  // out = h + g @ w2^T + b2   (split-K=4 -> bf16 partials -> reduce)
  gemm_nt<EPI_BF16_PART><<<dim3(8, 32, 4), 256, 0, stream>>>(
      gbuf, w2b, nullptr, w2P, nullptr, nullptr, TOK, 1024, 4096);
  reduce_w2_kernel<<<4096, 256, 0, stream>>>(w2P, hbuf, b2, out);
}

// Round 6
// 439.466 us; speedup vs baseline: 1.2047x; 1.0598x over previous
//
#include <hip/hip_runtime.h>
#include <math.h>

typedef unsigned short u16;
typedef __attribute__((ext_vector_type(8))) __bf16 bf16x8v;
typedef __attribute__((ext_vector_type(8))) unsigned short ushort8v;
typedef __attribute__((ext_vector_type(4))) unsigned short ushort4v;
typedef __attribute__((ext_vector_type(4))) float f32x4v;

#define D_EMBD 1024
#define NHEADS 16
#define DHEAD  64
#define DFF    4096
#define BATCHN 2
#define SEQL   2048
#define TOK    (BATCHN*SEQL)

#define EPI_F32_BIAS_RES 1
#define EPI_BF16_GELU    2
#define EPI_BF16_QKV     3   // bf16 out; Q columns (gc<1024) scaled by 0.125
#define EPI_F32_PART     4   // split-K: f32 partial at Cf + z*M*N
#define EPI_BF16_PART    5   // split-K: bf16 partial at Cb + z*M*N

__device__ __forceinline__ float bf2f(u16 s) {
  return __builtin_bit_cast(float, (unsigned)s << 16);
}
__device__ __forceinline__ u16 f2bf(float f) {
  unsigned u = __builtin_bit_cast(unsigned, f);
  unsigned r = u + 0x7fffu + ((u >> 16) & 1u);
  return (u16)(r >> 16);
}
__device__ __forceinline__ u16 f2bf_trunc(float f) {
  return (u16)(__builtin_bit_cast(unsigned, f) >> 16);
}

// async global->LDS, 16B per lane; LDS dest = wave-uniform base + lane*16
#define GLOAD16(gp, lp)                                                        \
  __builtin_amdgcn_global_load_lds(                                            \
      (__attribute__((address_space(1))) void*)(void*)(gp),                    \
      (__attribute__((address_space(3))) void*)(void*)(lp), 16, 0, 0)

// f32x4 -> bf16x4 elementwise (weights)
__global__ __launch_bounds__(256) void cvt_kernel(const float* __restrict__ src,
                                                  u16* __restrict__ dst, int n4) {
  int i = blockIdx.x * 256 + threadIdx.x;
  if (i < n4) {
    float4 v = ((const float4*)src)[i];
    ushort4 o;
    o.x = f2bf(v.x); o.y = f2bf(v.y); o.z = f2bf(v.z); o.w = f2bf(v.w);
    ((ushort4*)dst)[i] = o;
  }
}

// LayerNorm over D=1024, one block per row, writes bf16
__global__ __launch_bounds__(256) void ln_kernel(const float* __restrict__ x,
                                                 const float* __restrict__ sc,
                                                 const float* __restrict__ sh,
                                                 u16* __restrict__ out) {
  int row = blockIdx.x, tid = threadIdx.x;
  const float4* xr = (const float4*)(x + (size_t)row * D_EMBD);
  float4 v = xr[tid];
  float s  = (v.x + v.y) + (v.z + v.w);
  float s2 = (v.x * v.x + v.y * v.y) + (v.z * v.z + v.w * v.w);
#pragma unroll
  for (int off = 32; off; off >>= 1) {
    s  += __shfl_xor(s, off, 64);
    s2 += __shfl_xor(s2, off, 64);
  }
  __shared__ float rs[4], rs2[4];
  int wave = tid >> 6, lane = tid & 63;
  if (lane == 0) { rs[wave] = s; rs2[wave] = s2; }
  __syncthreads();
  s  = (rs[0] + rs[1]) + (rs[2] + rs[3]);
  s2 = (rs2[0] + rs2[1]) + (rs2[2] + rs2[3]);
  float mean = s * (1.f / 1024.f);
  float var  = s2 * (1.f / 1024.f) - mean * mean;
  float rstd = rsqrtf(var + 1e-6f);
  float4 scv = ((const float4*)sc)[tid];
  float4 shv = ((const float4*)sh)[tid];
  u16* op = out + (size_t)row * D_EMBD + tid * 4;
  op[0] = f2bf((v.x - mean) * rstd * scv.x + shv.x);
  op[1] = f2bf((v.y - mean) * rstd * scv.y + shv.y);
  op[2] = f2bf((v.z - mean) * rstd * scv.z + shv.z);
  op[3] = f2bf((v.w - mean) * rstd * scv.w + shv.w);
}

// split-K reduce for wo: h = p0 + p1 + bias + resid   (f32 partials, N=1024)
__global__ __launch_bounds__(256) void reduce_wo_kernel(const float* __restrict__ parts,
                                                        const float* __restrict__ resid,
                                                        const float* __restrict__ bias,
                                                        float* __restrict__ out) {
  int i = blockIdx.x * 256 + threadIdx.x;
  const float4* p0 = (const float4*)parts;
  const float4* p1 = p0 + (1 << 20);
  float4 a = p0[i], b = p1[i];
  float4 r = ((const float4*)resid)[i];
  float4 bi = ((const float4*)bias)[i & 255];
  float4 o;
  o.x = a.x + b.x + r.x + bi.x;
  o.y = a.y + b.y + r.y + bi.y;
  o.z = a.z + b.z + r.z + bi.z;
  o.w = a.w + b.w + r.w + bi.w;
  ((float4*)out)[i] = o;
}

// split-K reduce for w2: out = sum_{4} bf16 partials + bias + resid
__global__ __launch_bounds__(256) void reduce_w2_kernel(const u16* __restrict__ parts,
                                                        const float* __restrict__ resid,
                                                        const float* __restrict__ bias,
                                                        float* __restrict__ out) {
  int i = blockIdx.x * 256 + threadIdx.x;
  float4 r = ((const float4*)resid)[i];
  float4 bi = ((const float4*)bias)[i & 255];
  float s0 = 0, s1 = 0, s2 = 0, s3 = 0;
#pragma unroll
  for (int p = 0; p < 4; ++p) {
    ushort4 u = ((const ushort4*)(parts + (size_t)p * 4194304))[i];
    s0 += bf2f(u.x); s1 += bf2f(u.y); s2 += bf2f(u.z); s3 += bf2f(u.w);
  }
  float4 o = {s0 + r.x + bi.x, s1 + r.y + bi.y, s2 + r.z + bi.z, s3 + r.w + bi.w};
  ((float4*)out)[i] = o;
}

// C[M,N] = A[M,K] @ W[N,K]^T, bf16, f32 acc, fused epilogues.
template <int EPI>
__global__ __launch_bounds__(256) void gemm_nt(const u16* __restrict__ A,
                                               const u16* __restrict__ W,
                                               float* __restrict__ Cf,
                                               u16* __restrict__ Cb,
                                               const float* __restrict__ bias,
                                               const float* __restrict__ resid,
                                               int M, int N, int K) {
  __shared__ u16 As[8192];  // 16 KB
  __shared__ u16 Ws[8192];
  int tid = threadIdx.x;
  int wave = tid >> 6, lane = tid & 63;
  int wm = wave >> 1, wn = wave & 1;
  int lr = lane & 15, quad = lane >> 4;
  int m0 = blockIdx.y * 128, n0 = blockIdx.x * 128;
  int KC = K / gridDim.z;
  int kbeg = blockIdx.z * KC, kend = kbeg + KC;
  size_t poff = (size_t)blockIdx.z * M * N;

  f32x4v acc[4][4];
#pragma unroll
  for (int i = 0; i < 4; i++)
#pragma unroll
    for (int j = 0; j < 4; j++) {
      f32x4v z = {0.f, 0.f, 0.f, 0.f};
      acc[i][j] = z;
    }

  for (int k0 = kbeg; k0 < kend; k0 += 64) {
#pragma unroll
    for (int p = 0; p < 4; ++p) {
      int q = wave * 4 + p;
      int row = ((q >> 1) << 4) + lr;
      int col = k0 + (((q & 1) << 2) + quad) * 8;
      GLOAD16(A + (size_t)(m0 + row) * K + col, (char*)As + q * 1024);
      GLOAD16(W + (size_t)(n0 + row) * K + col, (char*)Ws + q * 1024);
    }
    __syncthreads();
    const bf16x8v* As4 = (const bf16x8v*)As;
    const bf16x8v* Ws4 = (const bf16x8v*)Ws;
#pragma unroll
    for (int kk = 0; kk < 2; ++kk) {
      bf16x8v af[4], bw[4];
#pragma unroll
      for (int i = 0; i < 4; i++) af[i] = As4[(((wm * 4 + i) * 2 + kk) << 6) + lane];
#pragma unroll
      for (int j = 0; j < 4; j++) bw[j] = Ws4[(((wn * 4 + j) * 2 + kk) << 6) + lane];
#pragma unroll
      for (int i = 0; i < 4; i++)
#pragma unroll
        for (int j = 0; j < 4; j++)
          acc[i][j] = __builtin_amdgcn_mfma_f32_16x16x32_bf16(af[i], bw[j], acc[i][j], 0, 0, 0);
    }
    __syncthreads();
  }

#pragma unroll
  for (int i = 0; i < 4; i++) {
#pragma unroll
    for (int j = 0; j < 4; j++) {
#pragma unroll
      for (int r = 0; r < 4; r++) {
        int gr = m0 + wm * 64 + i * 16 + quad * 4 + r;
        int gc = n0 + wn * 64 + j * 16 + lr;
        size_t idx = (size_t)gr * N + gc;
        float v = acc[i][j][r];
        if constexpr (EPI == EPI_F32_BIAS_RES) {
          Cf[idx] = v + bias[gc] + resid[idx];
        } else if constexpr (EPI == EPI_F32_PART) {
          Cf[poff + idx] = v;
        } else if constexpr (EPI == EPI_BF16_PART) {
          Cb[poff + idx] = f2bf(v);
        } else if constexpr (EPI == EPI_BF16_QKV) {
          Cb[idx] = f2bf(gc < 1024 ? v * 0.125f : v);
        } else {
          v += bias[gc];
          float z = 0.7978845608028654f * (v + 0.044715f * v * v * v);
          float t = 2.f / (1.f + __expf(-2.f * z)) - 1.f;
          Cb[idx] = f2bf(0.5f * v * (1.f + t));
        }
      }
    }
  }
}

// ---------------- MFMA flash attention (causal), S^T formulation ----------
// S^T = K.Q^T -> C layout [key=quad*4+r][q=lane&15]: softmax is per-LANE
// (15 in-lane ops + 2 cross-quad shuffles). The exp'd P feeds the PV MFMA
// DIRECTLY as the A operand under the virtual-k map phi(quad,j) =
// (2kk+(j>>2))*16 + quad*4 + (j&3)  -- no LDS round trip for P.
// V^T staged with swizzle col' = key ^ ((dim>>3 & 7)<<2); PV B-fragments are
// two ds_read_b64 per MFMA using the same phi. LPT block order (t descending).
#define VTS 72
__device__ __forceinline__ void stage_k(const u16* Kbase, int ks, u16* kfbuf,
                                        int wave, int lr, int quad) {
#pragma unroll
  for (int p = 0; p < 2; ++p) {
    int q = wave * 2 + p;
    int key = ((q >> 1) << 4) + lr;
    int c8 = ((q & 1) << 2) + quad;
    GLOAD16(Kbase + (size_t)(ks + key) * 3072 + c8 * 8, (char*)kfbuf + q * 1024);
  }
}
__device__ __forceinline__ void load_v(const u16* Vbase, int ks, int vkey0, int vc8,
                                       ushort8v& va, ushort8v& vb) {
  va = *(const ushort8v*)(Vbase + (size_t)(ks + vkey0) * 3072 + vc8 * 8);
  vb = *(const ushort8v*)(Vbase + (size_t)(ks + vkey0 + 1) * 3072 + vc8 * 8);
}
__device__ __forceinline__ void write_vt(u16* vt, int vc8, int vcol,
                                         ushort8v va, ushort8v vb) {
#pragma unroll
  for (int j = 0; j < 8; ++j) {
    unsigned pk = (unsigned)va[j] | ((unsigned)vb[j] << 16);
    *(unsigned*)(vt + (size_t)(vc8 * 8 + j) * VTS + vcol) = pk;
  }
}

__global__ __launch_bounds__(256) void attn_kernel(const u16* __restrict__ qkv,
                                                   u16* __restrict__ ctx) {
  __shared__ u16 Kf[2][4096];        // 16 KB, fragment order
  __shared__ u16 Vt[2][64 * VTS];    // 18 KB, V^T swizzled
  int tid = threadIdx.x;
  int wave = tid >> 6, lane = tid & 63;
  int lr = lane & 15, quad = lane >> 4;
  int id = blockIdx.x;
  int bh = id & 31;
  int t = 31 - (id >> 5);            // LPT: longest q-tiles dispatch first
  int b = bh >> 4, h = bh & 15;
  int q0 = t * 64;
  const u16* qkvb = qkv + (size_t)(b * SEQL) * 3072;
  int qrow = q0 + wave * 16 + lr;
  const u16* Qp = qkvb + (size_t)qrow * 3072 + h * 64 + quad * 8;
  bf16x8v qf0 = *(const bf16x8v*)(Qp);        // Q pre-scaled by 0.125 in GEMM
  bf16x8v qf1 = *(const bf16x8v*)(Qp + 32);
  const u16* Kbase = qkvb + 1024 + h * 64;
  const u16* Vbase = qkvb + 2048 + h * 64;
  int vkey0 = (tid >> 3) * 2, vc8 = tid & 7;
  int vcol = vkey0 ^ (vc8 << 2);

  float m = -INFINITY, l = 0.f;
  f32x4v accO[4];
#pragma unroll
  for (int r = 0; r < 4; r++) {
    f32x4v z = {0.f, 0.f, 0.f, 0.f};
    accO[r] = z;
  }

  int nkt = t + 1;
  {
    stage_k(Kbase, 0, Kf[0], wave, lr, quad);
    ushort8v va, vb;
    load_v(Vbase, 0, vkey0, vc8, va, vb);
    write_vt(Vt[0], vc8, vcol, va, vb);
  }
  __syncthreads();

  for (int kt = 0; kt < nkt; ++kt) {
    int cur = kt & 1, nxt = cur ^ 1;
    ushort8v va, vb;
    bool pre = (kt + 1 < nkt);
    if (pre) {
      stage_k(Kbase, (kt + 1) * 64, Kf[nxt], wave, lr, quad);
      load_v(Vbase, (kt + 1) * 64, vkey0, vc8, va, vb);
    }
    const bf16x8v* Kc = (const bf16x8v*)Kf[cur];
    const u16* Vc = Vt[cur];
    // ---- S^T = K Q^T  (A=K frag, B=Q frag) ----
    f32x4v accS[4];
#pragma unroll
    for (int jb = 0; jb < 4; jb++) {
      f32x4v z = {0.f, 0.f, 0.f, 0.f};
      accS[jb] = z;
    }
#pragma unroll
    for (int jb = 0; jb < 4; jb++) {
      accS[jb] = __builtin_amdgcn_mfma_f32_16x16x32_bf16(Kc[((jb * 2 + 0) << 6) + lane], qf0, accS[jb], 0, 0, 0);
      accS[jb] = __builtin_amdgcn_mfma_f32_16x16x32_bf16(Kc[((jb * 2 + 1) << 6) + lane], qf1, accS[jb], 0, 0, 0);
    }
    if (kt == t) {  // diagonal tile: mask key > q
#pragma unroll
      for (int jb = 0; jb < 4; jb++)
#pragma unroll
        for (int r = 0; r < 4; r++)
          if (jb * 16 + quad * 4 + r > wave * 16 + lr) accS[jb][r] = -INFINITY;
    }
    // ---- per-lane online softmax (q = lane&15) ----
    float smax = accS[0][0];
#pragma unroll
    for (int jb = 0; jb < 4; jb++)
#pragma unroll
      for (int r = 0; r < 4; r++) smax = fmaxf(smax, accS[jb][r]);
    smax = fmaxf(smax, __shfl_xor(smax, 16, 64));
    smax = fmaxf(smax, __shfl_xor(smax, 32, 64));
    float mn = fmaxf(m, smax);
    float alpha = __expf(m - mn);
    m = mn;
    float ps = 0.f;
#pragma unroll
    for (int jb = 0; jb < 4; jb++)
#pragma unroll
      for (int r = 0; r < 4; r++) {
        accS[jb][r] = __expf(accS[jb][r] - mn);
        ps += accS[jb][r];
      }
    ps += __shfl_xor(ps, 16, 64);
    ps += __shfl_xor(ps, 32, 64);
    l = l * alpha + ps;
    float ar[4];
#pragma unroll
    for (int r = 0; r < 4; r++) ar[r] = __shfl(alpha, quad * 4 + r, 16);
#pragma unroll
    for (int nb = 0; nb < 4; nb++)
#pragma unroll
      for (int r = 0; r < 4; r++) accO[nb][r] *= ar[r];
    // ---- O += P V  (A = packed P regs, B = V^T frags via phi) ----
#pragma unroll
    for (int kk = 0; kk < 2; ++kk) {
      ushort8v pp;
#pragma unroll
      for (int j = 0; j < 4; ++j) {
        pp[j]     = f2bf_trunc(accS[2 * kk][j]);
        pp[j + 4] = f2bf_trunc(accS[2 * kk + 1][j]);
      }
      bf16x8v pav = __builtin_bit_cast(bf16x8v, pp);
#pragma unroll
      for (int nb = 0; nb < 4; nb++) {
        int dim = nb * 16 + lr;
        int f = (nb * 2 + (lr >> 3)) & 7;
        int col1 = (kk * 32 + quad * 4) ^ (f << 2);
        ushort4v v0 = *(const ushort4v*)(Vc + dim * VTS + col1);
        ushort4v v1 = *(const ushort4v*)(Vc + dim * VTS + (col1 ^ 16));
        ushort8v vv;
#pragma unroll
        for (int j = 0; j < 4; ++j) { vv[j] = v0[j]; vv[j + 4] = v1[j]; }
        accO[nb] = __builtin_amdgcn_mfma_f32_16x16x32_bf16(pav, __builtin_bit_cast(bf16x8v, vv), accO[nb], 0, 0, 0);
      }
    }
    if (pre) write_vt(Vt[nxt], vc8, vcol, va, vb);
    __syncthreads();  // single barrier per tile
  }
  // ---- epilogue: O / l ----
  float linv = 1.f / l;
  float rr[4];
#pragma unroll
  for (int r = 0; r < 4; r++) rr[r] = __shfl(linv, quad * 4 + r, 16);
#pragma unroll
  for (int nb = 0; nb < 4; nb++)
#pragma unroll
    for (int r = 0; r < 4; r++) {
      int rowg = q0 + wave * 16 + quad * 4 + r;
      ctx[(size_t)(b * SEQL + rowg) * D_EMBD + h * 64 + nb * 16 + lr] =
          f2bf(accO[nb][r] * rr[r]);
    }
}

extern "C" void kernel_launch(void* const* d_in, const int* in_sizes, int n_in,
                              void* d_out, int out_size, void* d_ws, size_t ws_size,
                              hipStream_t stream) {
  const float* x    = (const float*)d_in[0];
  const float* wq   = (const float*)d_in[1];
  const float* wk   = (const float*)d_in[2];
  const float* wv   = (const float*)d_in[3];
  const float* wo   = (const float*)d_in[4];
  const float* bo   = (const float*)d_in[5];
  const float* w1   = (const float*)d_in[6];
  const float* b1   = (const float*)d_in[7];
  const float* w2   = (const float*)d_in[8];
  const float* b2   = (const float*)d_in[9];
  const float* ln1s = (const float*)d_in[10];
  const float* ln1b = (const float*)d_in[11];
  const float* ln2s = (const float*)d_in[12];
  const float* ln2b = (const float*)d_in[13];
  float* out = (float*)d_out;

  char* base = (char*)d_ws;
  size_t off = 0;
  auto alloc = [&](size_t bytes) {
    char* r = base + off;
    off += (bytes + 255) & ~(size_t)255;
    return r;
  };
  u16*   wcat = (u16*)alloc((size_t)3072 * 1024 * 2);
  u16*   wob  = (u16*)alloc((size_t)1024 * 1024 * 2);
  u16*   w1b  = (u16*)alloc((size_t)4096 * 1024 * 2);
  u16*   w2b  = (u16*)alloc((size_t)1024 * 4096 * 2);
  u16*   xn   = (u16*)alloc((size_t)TOK * 1024 * 2);   // 8 MB
  u16*   qkv  = (u16*)alloc((size_t)TOK * 3072 * 2);   // 24 MB
  u16*   ctx  = (u16*)alloc((size_t)TOK * 1024 * 2);
  float* hbuf = (float*)alloc((size_t)TOK * 1024 * 4);
  u16*   ybuf = (u16*)alloc((size_t)TOK * 1024 * 2);
  u16*   gbuf = (u16*)alloc((size_t)TOK * 4096 * 2);
  // split-K partials overlay the dead xn+qkv region (32 MB)
  float* woP = (float*)xn;
  u16*   w2P = (u16*)xn;

  cvt_kernel<<<1024, 256, 0, stream>>>(wq, wcat, 256 * 1024);
  cvt_kernel<<<1024, 256, 0, stream>>>(wk, wcat + 1024 * 1024, 256 * 1024);
  cvt_kernel<<<1024, 256, 0, stream>>>(wv, wcat + 2 * 1024 * 1024, 256 * 1024);
  cvt_kernel<<<1024, 256, 0, stream>>>(wo, wob, 256 * 1024);
  cvt_kernel<<<4096, 256, 0, stream>>>(w1, w1b, 1024 * 1024);
  cvt_kernel<<<4096, 256, 0, stream>>>(w2, w2b, 1024 * 1024);

  ln_kernel<<<TOK, 256, 0, stream>>>(x, ln1s, ln1b, xn);
  gemm_nt<EPI_BF16_QKV><<<dim3(24, 32), 256, 0, stream>>>(
      xn, wcat, nullptr, qkv, nullptr, nullptr, TOK, 3072, 1024);
  attn_kernel<<<1024, 256, 0, stream>>>(qkv, ctx);
  gemm_nt<EPI_F32_PART><<<dim3(8, 32, 2), 256, 0, stream>>>(
      ctx, wob, woP, nullptr, nullptr, nullptr, TOK, 1024, 1024);
  reduce_wo_kernel<<<4096, 256, 0, stream>>>(woP, x, bo, hbuf);
  ln_kernel<<<TOK, 256, 0, stream>>>(hbuf, ln2s, ln2b, ybuf);
  gemm_nt<EPI_BF16_GELU><<<dim3(32, 32), 256, 0, stream>>>(
      ybuf, w1b, nullptr, gbuf, b1, nullptr, TOK, 4096, 1024);
  gemm_nt<EPI_BF16_PART><<<dim3(8, 32, 4), 256, 0, stream>>>(
      gbuf, w2b, nullptr, w2P, nullptr, nullptr, TOK, 1024, 4096);
  reduce_w2_kernel<<<4096, 256, 0, stream>>>(w2P, hbuf, b2, out);
}

// Round 7
// 433.744 us; speedup vs baseline: 1.2206x; 1.0132x over previous
//
#include <hip/hip_runtime.h>
#include <math.h>

typedef unsigned short u16;
typedef __attribute__((ext_vector_type(8))) __bf16 bf16x8v;
typedef __attribute__((ext_vector_type(8))) unsigned short ushort8v;
typedef __attribute__((ext_vector_type(4))) unsigned short ushort4v;
typedef __attribute__((ext_vector_type(4))) float f32x4v;

#define D_EMBD 1024
#define NHEADS 16
#define DHEAD  64
#define DFF    4096
#define BATCHN 2
#define SEQL   2048
#define TOK    (BATCHN*SEQL)

#define EPI_BF16_GELU    2
#define EPI_BF16_QKV     3   // bf16 out; Q columns (gc<1024) scaled by 0.125
#define EPI_BF16_PART    5   // split-K: bf16 partial at Cb + z*M*N

__device__ __forceinline__ float bf2f(u16 s) {
  return __builtin_bit_cast(float, (unsigned)s << 16);
}
__device__ __forceinline__ u16 f2bf(float f) {
  unsigned u = __builtin_bit_cast(unsigned, f);
  unsigned r = u + 0x7fffu + ((u >> 16) & 1u);
  return (u16)(r >> 16);
}
__device__ __forceinline__ u16 f2bf_trunc(float f) {
  return (u16)(__builtin_bit_cast(unsigned, f) >> 16);
}

// async global->LDS, 16B per lane; LDS dest = wave-uniform base + lane*16
#define GLOAD16(gp, lp)                                                        \
  __builtin_amdgcn_global_load_lds(                                            \
      (__attribute__((address_space(1))) void*)(void*)(gp),                    \
      (__attribute__((address_space(3))) void*)(void*)(lp), 16, 0, 0)

// f32x4 -> bf16x4 elementwise (single weight matrix)
__global__ __launch_bounds__(256) void cvt_kernel(const float* __restrict__ src,
                                                  u16* __restrict__ dst, int n4) {
  int i = blockIdx.x * 256 + threadIdx.x;
  if (i < n4) {
    float4 v = ((const float4*)src)[i];
    ushort4 o;
    o.x = f2bf(v.x); o.y = f2bf(v.y); o.z = f2bf(v.z); o.w = f2bf(v.w);
    ((ushort4*)dst)[i] = o;
  }
}

// fused conversion of wq/wk/wv -> wcat and wo -> wob (4096 blocks)
__global__ __launch_bounds__(256) void cvt4_kernel(const float* __restrict__ wq,
                                                   const float* __restrict__ wk,
                                                   const float* __restrict__ wv,
                                                   const float* __restrict__ wo,
                                                   u16* __restrict__ wcat,
                                                   u16* __restrict__ wob) {
  int bid = blockIdx.x;
  int seg = bid >> 10;
  int loc = (bid & 1023) * 256 + threadIdx.x;  // float4 index within 1M-elem matrix
  const float* src = (seg == 0) ? wq : (seg == 1) ? wk : (seg == 2) ? wv : wo;
  u16* dst = (seg == 0) ? wcat : (seg == 1) ? wcat + 1048576
                                : (seg == 2) ? wcat + 2097152 : wob;
  float4 v = ((const float4*)src)[loc];
  ushort4 o;
  o.x = f2bf(v.x); o.y = f2bf(v.y); o.z = f2bf(v.z); o.w = f2bf(v.w);
  ((ushort4*)dst)[loc] = o;
}

// LayerNorm over D=1024, one block per row, writes bf16
__global__ __launch_bounds__(256) void ln_kernel(const float* __restrict__ x,
                                                 const float* __restrict__ sc,
                                                 const float* __restrict__ sh,
                                                 u16* __restrict__ out) {
  int row = blockIdx.x, tid = threadIdx.x;
  const float4* xr = (const float4*)(x + (size_t)row * D_EMBD);
  float4 v = xr[tid];
  float s  = (v.x + v.y) + (v.z + v.w);
  float s2 = (v.x * v.x + v.y * v.y) + (v.z * v.z + v.w * v.w);
#pragma unroll
  for (int off = 32; off; off >>= 1) {
    s  += __shfl_xor(s, off, 64);
    s2 += __shfl_xor(s2, off, 64);
  }
  __shared__ float rs[4], rs2[4];
  int wave = tid >> 6, lane = tid & 63;
  if (lane == 0) { rs[wave] = s; rs2[wave] = s2; }
  __syncthreads();
  s  = (rs[0] + rs[1]) + (rs[2] + rs[3]);
  s2 = (rs2[0] + rs2[1]) + (rs2[2] + rs2[3]);
  float mean = s * (1.f / 1024.f);
  float var  = s2 * (1.f / 1024.f) - mean * mean;
  float rstd = rsqrtf(var + 1e-6f);
  float4 scv = ((const float4*)sc)[tid];
  float4 shv = ((const float4*)sh)[tid];
  ushort4 o;
  o.x = f2bf((v.x - mean) * rstd * scv.x + shv.x);
  o.y = f2bf((v.y - mean) * rstd * scv.y + shv.y);
  o.z = f2bf((v.z - mean) * rstd * scv.z + shv.z);
  o.w = f2bf((v.w - mean) * rstd * scv.w + shv.w);
  ((ushort4*)(out + (size_t)row * D_EMBD))[tid] = o;
}

// Fused: h = x + (sum of 4 bf16 wo partials) + bo; write hbuf(f32);
// then LayerNorm(h) -> ybuf(bf16). One block per row.
__global__ __launch_bounds__(256) void ln2f_kernel(const u16* __restrict__ parts,
                                                   const float* __restrict__ x,
                                                   const float* __restrict__ bo,
                                                   const float* __restrict__ sc,
                                                   const float* __restrict__ sh,
                                                   float* __restrict__ hbuf,
                                                   u16* __restrict__ ybuf) {
  int row = blockIdx.x, tid = threadIdx.x;
  size_t base4 = (size_t)row * 256 + tid;   // float4 / ushort4 index
  float4 v = ((const float4*)x)[base4];
  float4 bv = ((const float4*)bo)[tid];
  v.x += bv.x; v.y += bv.y; v.z += bv.z; v.w += bv.w;
#pragma unroll
  for (int p = 0; p < 4; ++p) {
    ushort4 u = ((const ushort4*)parts)[(size_t)p * 1048576 + base4];
    v.x += bf2f(u.x); v.y += bf2f(u.y); v.z += bf2f(u.z); v.w += bf2f(u.w);
  }
  ((float4*)hbuf)[base4] = v;
  float s  = (v.x + v.y) + (v.z + v.w);
  float s2 = (v.x * v.x + v.y * v.y) + (v.z * v.z + v.w * v.w);
#pragma unroll
  for (int off = 32; off; off >>= 1) {
    s  += __shfl_xor(s, off, 64);
    s2 += __shfl_xor(s2, off, 64);
  }
  __shared__ float rs[4], rs2[4];
  int wave = tid >> 6, lane = tid & 63;
  if (lane == 0) { rs[wave] = s; rs2[wave] = s2; }
  __syncthreads();
  s  = (rs[0] + rs[1]) + (rs[2] + rs[3]);
  s2 = (rs2[0] + rs2[1]) + (rs2[2] + rs2[3]);
  float mean = s * (1.f / 1024.f);
  float var  = s2 * (1.f / 1024.f) - mean * mean;
  float rstd = rsqrtf(var + 1e-6f);
  float4 scv = ((const float4*)sc)[tid];
  float4 shv = ((const float4*)sh)[tid];
  ushort4 o;
  o.x = f2bf((v.x - mean) * rstd * scv.x + shv.x);
  o.y = f2bf((v.y - mean) * rstd * scv.y + shv.y);
  o.z = f2bf((v.z - mean) * rstd * scv.z + shv.z);
  o.w = f2bf((v.w - mean) * rstd * scv.w + shv.w);
  ((ushort4*)ybuf)[base4] = o;
}

// split-K reduce for w2: out = sum_{4} bf16 partials + bias + resid
__global__ __launch_bounds__(256) void reduce_w2_kernel(const u16* __restrict__ parts,
                                                        const float* __restrict__ resid,
                                                        const float* __restrict__ bias,
                                                        float* __restrict__ out) {
  int i = blockIdx.x * 256 + threadIdx.x;
  float4 r = ((const float4*)resid)[i];
  float4 bi = ((const float4*)bias)[i & 255];
  float s0 = 0, s1 = 0, s2 = 0, s3 = 0;
#pragma unroll
  for (int p = 0; p < 4; ++p) {
    ushort4 u = ((const ushort4*)parts)[(size_t)p * 1048576 + i];
    s0 += bf2f(u.x); s1 += bf2f(u.y); s2 += bf2f(u.z); s3 += bf2f(u.w);
  }
  float4 o = {s0 + r.x + bi.x, s1 + r.y + bi.y, s2 + r.z + bi.z, s3 + r.w + bi.w};
  ((float4*)out)[i] = o;
}

// C[M,N] = A[M,K] @ W[N,K]^T, bf16, f32 acc, fused epilogues.
template <int EPI>
__global__ __launch_bounds__(256) void gemm_nt(const u16* __restrict__ A,
                                               const u16* __restrict__ W,
                                               float* __restrict__ Cf,
                                               u16* __restrict__ Cb,
                                               const float* __restrict__ bias,
                                               int M, int N, int K) {
  __shared__ u16 As[8192];  // 16 KB
  __shared__ u16 Ws[8192];
  int tid = threadIdx.x;
  int wave = tid >> 6, lane = tid & 63;
  int wm = wave >> 1, wn = wave & 1;
  int lr = lane & 15, quad = lane >> 4;
  int m0 = blockIdx.y * 128, n0 = blockIdx.x * 128;
  int KC = K / gridDim.z;
  int kbeg = blockIdx.z * KC, kend = kbeg + KC;
  size_t poff = (size_t)blockIdx.z * M * N;

  f32x4v acc[4][4];
#pragma unroll
  for (int i = 0; i < 4; i++)
#pragma unroll
    for (int j = 0; j < 4; j++) {
      f32x4v z = {0.f, 0.f, 0.f, 0.f};
      acc[i][j] = z;
    }

  for (int k0 = kbeg; k0 < kend; k0 += 64) {
#pragma unroll
    for (int p = 0; p < 4; ++p) {
      int q = wave * 4 + p;
      int row = ((q >> 1) << 4) + lr;
      int col = k0 + (((q & 1) << 2) + quad) * 8;
      GLOAD16(A + (size_t)(m0 + row) * K + col, (char*)As + q * 1024);
      GLOAD16(W + (size_t)(n0 + row) * K + col, (char*)Ws + q * 1024);
    }
    __syncthreads();
    const bf16x8v* As4 = (const bf16x8v*)As;
    const bf16x8v* Ws4 = (const bf16x8v*)Ws;
#pragma unroll
    for (int kk = 0; kk < 2; ++kk) {
      bf16x8v af[4], bw[4];
#pragma unroll
      for (int i = 0; i < 4; i++) af[i] = As4[(((wm * 4 + i) * 2 + kk) << 6) + lane];
#pragma unroll
      for (int j = 0; j < 4; j++) bw[j] = Ws4[(((wn * 4 + j) * 2 + kk) << 6) + lane];
#pragma unroll
      for (int i = 0; i < 4; i++)
#pragma unroll
        for (int j = 0; j < 4; j++)
          acc[i][j] = __builtin_amdgcn_mfma_f32_16x16x32_bf16(af[i], bw[j], acc[i][j], 0, 0, 0);
    }
    __syncthreads();
  }

#pragma unroll
  for (int i = 0; i < 4; i++) {
#pragma unroll
    for (int j = 0; j < 4; j++) {
#pragma unroll
      for (int r = 0; r < 4; r++) {
        int gr = m0 + wm * 64 + i * 16 + quad * 4 + r;
        int gc = n0 + wn * 64 + j * 16 + lr;
        size_t idx = (size_t)gr * N + gc;
        float v = acc[i][j][r];
        if constexpr (EPI == EPI_BF16_PART) {
          Cb[poff + idx] = f2bf(v);
        } else if constexpr (EPI == EPI_BF16_QKV) {
          Cb[idx] = f2bf(gc < 1024 ? v * 0.125f : v);
        } else {  // EPI_BF16_GELU
          v += bias[gc];
          float z = 0.7978845608028654f * (v + 0.044715f * v * v * v);
          float t = 2.f / (1.f + __expf(-2.f * z)) - 1.f;
          Cb[idx] = f2bf(0.5f * v * (1.f + t));
        }
      }
    }
  }
}

// ---------------- MFMA flash attention (causal), S^T formulation ----------
#define VTS 72
__device__ __forceinline__ void stage_k(const u16* Kbase, int ks, u16* kfbuf,
                                        int wave, int lr, int quad) {
#pragma unroll
  for (int p = 0; p < 2; ++p) {
    int q = wave * 2 + p;
    int key = ((q >> 1) << 4) + lr;
    int c8 = ((q & 1) << 2) + quad;
    GLOAD16(Kbase + (size_t)(ks + key) * 3072 + c8 * 8, (char*)kfbuf + q * 1024);
  }
}
__device__ __forceinline__ void load_v(const u16* Vbase, int ks, int vkey0, int vc8,
                                       ushort8v& va, ushort8v& vb) {
  va = *(const ushort8v*)(Vbase + (size_t)(ks + vkey0) * 3072 + vc8 * 8);
  vb = *(const ushort8v*)(Vbase + (size_t)(ks + vkey0 + 1) * 3072 + vc8 * 8);
}
__device__ __forceinline__ void write_vt(u16* vt, int vc8, int vcol,
                                         ushort8v va, ushort8v vb) {
#pragma unroll
  for (int j = 0; j < 8; ++j) {
    unsigned pk = (unsigned)va[j] | ((unsigned)vb[j] << 16);
    *(unsigned*)(vt + (size_t)(vc8 * 8 + j) * VTS + vcol) = pk;
  }
}

__global__ __launch_bounds__(256) void attn_kernel(const u16* __restrict__ qkv,
                                                   u16* __restrict__ ctx) {
  __shared__ u16 Kf[2][4096];        // 16 KB, fragment order
  __shared__ u16 Vt[2][64 * VTS];    // 18 KB, V^T swizzled
  int tid = threadIdx.x;
  int wave = tid >> 6, lane = tid & 63;
  int lr = lane & 15, quad = lane >> 4;
  int id = blockIdx.x;
  int bh = id & 31;
  int t = 31 - (id >> 5);            // LPT: longest q-tiles dispatch first
  int b = bh >> 4, h = bh & 15;
  int q0 = t * 64;
  const u16* qkvb = qkv + (size_t)(b * SEQL) * 3072;
  int qrow = q0 + wave * 16 + lr;
  const u16* Qp = qkvb + (size_t)qrow * 3072 + h * 64 + quad * 8;
  bf16x8v qf0 = *(const bf16x8v*)(Qp);        // Q pre-scaled by 0.125 in GEMM
  bf16x8v qf1 = *(const bf16x8v*)(Qp + 32);
  const u16* Kbase = qkvb + 1024 + h * 64;
  const u16* Vbase = qkvb + 2048 + h * 64;
  int vkey0 = (tid >> 3) * 2, vc8 = tid & 7;
  int vcol = vkey0 ^ (vc8 << 2);

  float m = -INFINITY, l = 0.f;
  f32x4v accO[4];
#pragma unroll
  for (int r = 0; r < 4; r++) {
    f32x4v z = {0.f, 0.f, 0.f, 0.f};
    accO[r] = z;
  }

  int nkt = t + 1;
  {
    stage_k(Kbase, 0, Kf[0], wave, lr, quad);
    ushort8v va, vb;
    load_v(Vbase, 0, vkey0, vc8, va, vb);
    write_vt(Vt[0], vc8, vcol, va, vb);
  }
  __syncthreads();

  for (int kt = 0; kt < nkt; ++kt) {
    int cur = kt & 1, nxt = cur ^ 1;
    ushort8v va, vb;
    bool pre = (kt + 1 < nkt);
    if (pre) {
      stage_k(Kbase, (kt + 1) * 64, Kf[nxt], wave, lr, quad);
      load_v(Vbase, (kt + 1) * 64, vkey0, vc8, va, vb);
    }
    const bf16x8v* Kc = (const bf16x8v*)Kf[cur];
    const u16* Vc = Vt[cur];
    // ---- S^T = K Q^T ----
    f32x4v accS[4];
#pragma unroll
    for (int jb = 0; jb < 4; jb++) {
      f32x4v z = {0.f, 0.f, 0.f, 0.f};
      accS[jb] = z;
    }
#pragma unroll
    for (int jb = 0; jb < 4; jb++) {
      accS[jb] = __builtin_amdgcn_mfma_f32_16x16x32_bf16(Kc[((jb * 2 + 0) << 6) + lane], qf0, accS[jb], 0, 0, 0);
      accS[jb] = __builtin_amdgcn_mfma_f32_16x16x32_bf16(Kc[((jb * 2 + 1) << 6) + lane], qf1, accS[jb], 0, 0, 0);
    }
    if (kt == t) {  // diagonal tile: mask key > q
#pragma unroll
      for (int jb = 0; jb < 4; jb++)
#pragma unroll
        for (int r = 0; r < 4; r++)
          if (jb * 16 + quad * 4 + r > wave * 16 + lr) accS[jb][r] = -INFINITY;
    }
    // ---- per-lane online softmax (q = lane&15) ----
    float smax = accS[0][0];
#pragma unroll
    for (int jb = 0; jb < 4; jb++)
#pragma unroll
      for (int r = 0; r < 4; r++) smax = fmaxf(smax, accS[jb][r]);
    smax = fmaxf(smax, __shfl_xor(smax, 16, 64));
    smax = fmaxf(smax, __shfl_xor(smax, 32, 64));
    float mn = fmaxf(m, smax);
    float alpha = __expf(m - mn);
    m = mn;
    float ps = 0.f;
#pragma unroll
    for (int jb = 0; jb < 4; jb++)
#pragma unroll
      for (int r = 0; r < 4; r++) {
        accS[jb][r] = __expf(accS[jb][r] - mn);
        ps += accS[jb][r];
      }
    ps += __shfl_xor(ps, 16, 64);
    ps += __shfl_xor(ps, 32, 64);
    l = l * alpha + ps;
    float ar[4];
#pragma unroll
    for (int r = 0; r < 4; r++) ar[r] = __shfl(alpha, quad * 4 + r, 16);
#pragma unroll
    for (int nb = 0; nb < 4; nb++)
#pragma unroll
      for (int r = 0; r < 4; r++) accO[nb][r] *= ar[r];
    // ---- O += P V ----
#pragma unroll
    for (int kk = 0; kk < 2; ++kk) {
      ushort8v pp;
#pragma unroll
      for (int j = 0; j < 4; ++j) {
        pp[j]     = f2bf_trunc(accS[2 * kk][j]);
        pp[j + 4] = f2bf_trunc(accS[2 * kk + 1][j]);
      }
      bf16x8v pav = __builtin_bit_cast(bf16x8v, pp);
#pragma unroll
      for (int nb = 0; nb < 4; nb++) {
        int dim = nb * 16 + lr;
        int f = (nb * 2 + (lr >> 3)) & 7;
        int col1 = (kk * 32 + quad * 4) ^ (f << 2);
        ushort4v v0 = *(const ushort4v*)(Vc + dim * VTS + col1);
        ushort4v v1 = *(const ushort4v*)(Vc + dim * VTS + (col1 ^ 16));
        ushort8v vv;
#pragma unroll
        for (int j = 0; j < 4; ++j) { vv[j] = v0[j]; vv[j + 4] = v1[j]; }
        accO[nb] = __builtin_amdgcn_mfma_f32_16x16x32_bf16(pav, __builtin_bit_cast(bf16x8v, vv), accO[nb], 0, 0, 0);
      }
    }
    if (pre) write_vt(Vt[nxt], vc8, vcol, va, vb);
    __syncthreads();  // single barrier per tile
  }
  float linv = 1.f / l;
  float rr[4];
#pragma unroll
  for (int r = 0; r < 4; r++) rr[r] = __shfl(linv, quad * 4 + r, 16);
#pragma unroll
  for (int nb = 0; nb < 4; nb++)
#pragma unroll
    for (int r = 0; r < 4; r++) {
      int rowg = q0 + wave * 16 + quad * 4 + r;
      ctx[(size_t)(b * SEQL + rowg) * D_EMBD + h * 64 + nb * 16 + lr] =
          f2bf(accO[nb][r] * rr[r]);
    }
}

extern "C" void kernel_launch(void* const* d_in, const int* in_sizes, int n_in,
                              void* d_out, int out_size, void* d_ws, size_t ws_size,
                              hipStream_t stream) {
  const float* x    = (const float*)d_in[0];
  const float* wq   = (const float*)d_in[1];
  const float* wk   = (const float*)d_in[2];
  const float* wv   = (const float*)d_in[3];
  const float* wo   = (const float*)d_in[4];
  const float* bo   = (const float*)d_in[5];
  const float* w1   = (const float*)d_in[6];
  const float* b1   = (const float*)d_in[7];
  const float* w2   = (const float*)d_in[8];
  const float* b2   = (const float*)d_in[9];
  const float* ln1s = (const float*)d_in[10];
  const float* ln1b = (const float*)d_in[11];
  const float* ln2s = (const float*)d_in[12];
  const float* ln2b = (const float*)d_in[13];
  float* out = (float*)d_out;

  char* base = (char*)d_ws;
  size_t off = 0;
  auto alloc = [&](size_t bytes) {
    char* r = base + off;
    off += (bytes + 255) & ~(size_t)255;
    return r;
  };
  u16*   wcat = (u16*)alloc((size_t)3072 * 1024 * 2);
  u16*   wob  = (u16*)alloc((size_t)1024 * 1024 * 2);
  u16*   w1b  = (u16*)alloc((size_t)4096 * 1024 * 2);
  u16*   w2b  = (u16*)alloc((size_t)1024 * 4096 * 2);
  u16*   xn   = (u16*)alloc((size_t)TOK * 1024 * 2);   // 8 MB
  u16*   qkv  = (u16*)alloc((size_t)TOK * 3072 * 2);   // 24 MB
  u16*   ctx  = (u16*)alloc((size_t)TOK * 1024 * 2);
  float* hbuf = (float*)alloc((size_t)TOK * 1024 * 4);
  u16*   ybuf = (u16*)alloc((size_t)TOK * 1024 * 2);
  u16*   gbuf = (u16*)alloc((size_t)TOK * 4096 * 2);
  // split-K bf16 partials (4 x 8 MB) overlay the dead xn+qkv region (32 MB):
  //   wo partials live attn->ln2f; w2 partials live w2gemm->reduce_w2.
  u16* woP = (u16*)xn;
  u16* w2P = (u16*)xn;

  // attention weights (used soon)
  cvt4_kernel<<<4096, 256, 0, stream>>>(wq, wk, wv, wo, wcat, wob);
  ln_kernel<<<TOK, 256, 0, stream>>>(x, ln1s, ln1b, xn);
  gemm_nt<EPI_BF16_QKV><<<dim3(24, 32), 256, 0, stream>>>(
      xn, wcat, nullptr, qkv, nullptr, TOK, 3072, 1024);
  attn_kernel<<<1024, 256, 0, stream>>>(qkv, ctx);
  // wo: split-K=4 bf16 partials (qkv region now dead)
  gemm_nt<EPI_BF16_PART><<<dim3(8, 32, 4), 256, 0, stream>>>(
      ctx, wob, nullptr, woP, nullptr, TOK, 1024, 1024);
  // fused: h = x + sum(partials) + bo -> hbuf; ln2(h) -> ybuf
  ln2f_kernel<<<TOK, 256, 0, stream>>>(woP, x, bo, ln2s, ln2b, hbuf, ybuf);
  // JIT-convert w1 so it is L2/L3-hot for the GEMM
  cvt_kernel<<<4096, 256, 0, stream>>>(w1, w1b, 1024 * 1024);
  gemm_nt<EPI_BF16_GELU><<<dim3(32, 32), 256, 0, stream>>>(
      ybuf, w1b, nullptr, gbuf, b1, TOK, 4096, 1024);
  // JIT-convert w2
  cvt_kernel<<<4096, 256, 0, stream>>>(w2, w2b, 1024 * 1024);
  gemm_nt<EPI_BF16_PART><<<dim3(8, 32, 4), 256, 0, stream>>>(
      gbuf, w2b, nullptr, w2P, nullptr, TOK, 1024, 4096);
  reduce_w2_kernel<<<4096, 256, 0, stream>>>(w2P, hbuf, b2, out);
}

// Round 8
// 429.037 us; speedup vs baseline: 1.2340x; 1.0110x over previous
//
#include <hip/hip_runtime.h>
#include <math.h>

typedef unsigned short u16;
typedef __attribute__((ext_vector_type(8))) __bf16 bf16x8v;
typedef __attribute__((ext_vector_type(8))) unsigned short ushort8v;
typedef __attribute__((ext_vector_type(4))) unsigned short ushort4v;
typedef __attribute__((ext_vector_type(4))) float f32x4v;

#define D_EMBD 1024
#define NHEADS 16
#define DHEAD  64
#define DFF    4096
#define BATCHN 2
#define SEQL   2048
#define TOK    (BATCHN*SEQL)

#define EPI_BF16_GELU    2
#define EPI_BF16_QKV     3   // bf16 out; Q columns (gc<1024) scaled by 0.125
#define EPI_BF16_PART    5   // split-K: bf16 partial at Cb + z*M*N

__device__ __forceinline__ float bf2f(u16 s) {
  return __builtin_bit_cast(float, (unsigned)s << 16);
}
__device__ __forceinline__ u16 f2bf(float f) {
  unsigned u = __builtin_bit_cast(unsigned, f);
  unsigned r = u + 0x7fffu + ((u >> 16) & 1u);
  return (u16)(r >> 16);
}
__device__ __forceinline__ u16 f2bf_trunc(float f) {
  return (u16)(__builtin_bit_cast(unsigned, f) >> 16);
}

// async global->LDS, 16B per lane; LDS dest = wave-uniform base + lane*16
#define GLOAD16(gp, lp)                                                        \
  __builtin_amdgcn_global_load_lds(                                            \
      (__attribute__((address_space(1))) void*)(void*)(gp),                    \
      (__attribute__((address_space(3))) void*)(void*)(lp), 16, 0, 0)

// One launch converts ALL weight matrices f32 -> bf16 at t=0 (writebacks
// complete long before the consumer GEMMs; JIT conversion regressed — R7).
// Segments (in 1024-block units of 256 float4): wq,wk,wv,wo (1 each), w1 (4), w2 (4).
__global__ __launch_bounds__(256) void cvt_all_kernel(const float* __restrict__ wq,
                                                      const float* __restrict__ wk,
                                                      const float* __restrict__ wv,
                                                      const float* __restrict__ wo,
                                                      const float* __restrict__ w1,
                                                      const float* __restrict__ w2,
                                                      u16* __restrict__ wcat,
                                                      u16* __restrict__ wob,
                                                      u16* __restrict__ w1b,
                                                      u16* __restrict__ w2b) {
  int bid = blockIdx.x;
  const float* src;
  u16* dst;
  int loc;
  if (bid < 4096) {
    int seg = bid >> 10;
    loc = (bid & 1023) * 256 + threadIdx.x;
    src = (seg == 0) ? wq : (seg == 1) ? wk : (seg == 2) ? wv : wo;
    dst = (seg == 0) ? wcat : (seg == 1) ? wcat + 1048576
                            : (seg == 2) ? wcat + 2097152 : wob;
  } else if (bid < 8192) {
    loc = (bid - 4096) * 256 + threadIdx.x;
    src = w1; dst = w1b;
  } else {
    loc = (bid - 8192) * 256 + threadIdx.x;
    src = w2; dst = w2b;
  }
  float4 v = ((const float4*)src)[loc];
  ushort4 o;
  o.x = f2bf(v.x); o.y = f2bf(v.y); o.z = f2bf(v.z); o.w = f2bf(v.w);
  ((ushort4*)dst)[loc] = o;
}

// LayerNorm over D=1024, one block per row, writes bf16
__global__ __launch_bounds__(256) void ln_kernel(const float* __restrict__ x,
                                                 const float* __restrict__ sc,
                                                 const float* __restrict__ sh,
                                                 u16* __restrict__ out) {
  int row = blockIdx.x, tid = threadIdx.x;
  const float4* xr = (const float4*)(x + (size_t)row * D_EMBD);
  float4 v = xr[tid];
  float s  = (v.x + v.y) + (v.z + v.w);
  float s2 = (v.x * v.x + v.y * v.y) + (v.z * v.z + v.w * v.w);
#pragma unroll
  for (int off = 32; off; off >>= 1) {
    s  += __shfl_xor(s, off, 64);
    s2 += __shfl_xor(s2, off, 64);
  }
  __shared__ float rs[4], rs2[4];
  int wave = tid >> 6, lane = tid & 63;
  if (lane == 0) { rs[wave] = s; rs2[wave] = s2; }
  __syncthreads();
  s  = (rs[0] + rs[1]) + (rs[2] + rs[3]);
  s2 = (rs2[0] + rs2[1]) + (rs2[2] + rs2[3]);
  float mean = s * (1.f / 1024.f);
  float var  = s2 * (1.f / 1024.f) - mean * mean;
  float rstd = rsqrtf(var + 1e-6f);
  float4 scv = ((const float4*)sc)[tid];
  float4 shv = ((const float4*)sh)[tid];
  ushort4 o;
  o.x = f2bf((v.x - mean) * rstd * scv.x + shv.x);
  o.y = f2bf((v.y - mean) * rstd * scv.y + shv.y);
  o.z = f2bf((v.z - mean) * rstd * scv.z + shv.z);
  o.w = f2bf((v.w - mean) * rstd * scv.w + shv.w);
  ((ushort4*)(out + (size_t)row * D_EMBD))[tid] = o;
}

// Fused: h = x + (sum of 4 bf16 wo partials) + bo; write hbuf(f32);
// then LayerNorm(h) -> ybuf(bf16). One block per row.
__global__ __launch_bounds__(256) void ln2f_kernel(const u16* __restrict__ parts,
                                                   const float* __restrict__ x,
                                                   const float* __restrict__ bo,
                                                   const float* __restrict__ sc,
                                                   const float* __restrict__ sh,
                                                   float* __restrict__ hbuf,
                                                   u16* __restrict__ ybuf) {
  int row = blockIdx.x, tid = threadIdx.x;
  size_t base4 = (size_t)row * 256 + tid;   // float4 / ushort4 index
  float4 v = ((const float4*)x)[base4];
  float4 bv = ((const float4*)bo)[tid];
  v.x += bv.x; v.y += bv.y; v.z += bv.z; v.w += bv.w;
#pragma unroll
  for (int p = 0; p < 4; ++p) {
    ushort4 u = ((const ushort4*)parts)[(size_t)p * 1048576 + base4];
    v.x += bf2f(u.x); v.y += bf2f(u.y); v.z += bf2f(u.z); v.w += bf2f(u.w);
  }
  ((float4*)hbuf)[base4] = v;
  float s  = (v.x + v.y) + (v.z + v.w);
  float s2 = (v.x * v.x + v.y * v.y) + (v.z * v.z + v.w * v.w);
#pragma unroll
  for (int off = 32; off; off >>= 1) {
    s  += __shfl_xor(s, off, 64);
    s2 += __shfl_xor(s2, off, 64);
  }
  __shared__ float rs[4], rs2[4];
  int wave = tid >> 6, lane = tid & 63;
  if (lane == 0) { rs[wave] = s; rs2[wave] = s2; }
  __syncthreads();
  s  = (rs[0] + rs[1]) + (rs[2] + rs[3]);
  s2 = (rs2[0] + rs2[1]) + (rs2[2] + rs2[3]);
  float mean = s * (1.f / 1024.f);
  float var  = s2 * (1.f / 1024.f) - mean * mean;
  float rstd = rsqrtf(var + 1e-6f);
  float4 scv = ((const float4*)sc)[tid];
  float4 shv = ((const float4*)sh)[tid];
  ushort4 o;
  o.x = f2bf((v.x - mean) * rstd * scv.x + shv.x);
  o.y = f2bf((v.y - mean) * rstd * scv.y + shv.y);
  o.z = f2bf((v.z - mean) * rstd * scv.z + shv.z);
  o.w = f2bf((v.w - mean) * rstd * scv.w + shv.w);
  ((ushort4*)ybuf)[base4] = o;
}

// split-K reduce for w2: out = sum_{4} bf16 partials + bias + resid
__global__ __launch_bounds__(256) void reduce_w2_kernel(const u16* __restrict__ parts,
                                                        const float* __restrict__ resid,
                                                        const float* __restrict__ bias,
                                                        float* __restrict__ out) {
  int i = blockIdx.x * 256 + threadIdx.x;
  float4 r = ((const float4*)resid)[i];
  float4 bi = ((const float4*)bias)[i & 255];
  float s0 = 0, s1 = 0, s2 = 0, s3 = 0;
#pragma unroll
  for (int p = 0; p < 4; ++p) {
    ushort4 u = ((const ushort4*)parts)[(size_t)p * 1048576 + i];
    s0 += bf2f(u.x); s1 += bf2f(u.y); s2 += bf2f(u.z); s3 += bf2f(u.w);
  }
  float4 o = {s0 + r.x + bi.x, s1 + r.y + bi.y, s2 + r.z + bi.z, s3 + r.w + bi.w};
  ((float4*)out)[i] = o;
}

// C[M,N] = A[M,K] @ W[N,K]^T, bf16, f32 acc, fused epilogues.
template <int EPI>
__global__ __launch_bounds__(256) void gemm_nt(const u16* __restrict__ A,
                                               const u16* __restrict__ W,
                                               float* __restrict__ Cf,
                                               u16* __restrict__ Cb,
                                               const float* __restrict__ bias,
                                               int M, int N, int K) {
  __shared__ u16 As[8192];  // 16 KB
  __shared__ u16 Ws[8192];
  int tid = threadIdx.x;
  int wave = tid >> 6, lane = tid & 63;
  int wm = wave >> 1, wn = wave & 1;
  int lr = lane & 15, quad = lane >> 4;
  int m0 = blockIdx.y * 128, n0 = blockIdx.x * 128;
  int KC = K / gridDim.z;
  int kbeg = blockIdx.z * KC, kend = kbeg + KC;
  size_t poff = (size_t)blockIdx.z * M * N;

  f32x4v acc[4][4];
#pragma unroll
  for (int i = 0; i < 4; i++)
#pragma unroll
    for (int j = 0; j < 4; j++) {
      f32x4v z = {0.f, 0.f, 0.f, 0.f};
      acc[i][j] = z;
    }

  for (int k0 = kbeg; k0 < kend; k0 += 64) {
#pragma unroll
    for (int p = 0; p < 4; ++p) {
      int q = wave * 4 + p;
      int row = ((q >> 1) << 4) + lr;
      int col = k0 + (((q & 1) << 2) + quad) * 8;
      GLOAD16(A + (size_t)(m0 + row) * K + col, (char*)As + q * 1024);
      GLOAD16(W + (size_t)(n0 + row) * K + col, (char*)Ws + q * 1024);
    }
    __syncthreads();
    const bf16x8v* As4 = (const bf16x8v*)As;
    const bf16x8v* Ws4 = (const bf16x8v*)Ws;
#pragma unroll
    for (int kk = 0; kk < 2; ++kk) {
      bf16x8v af[4], bw[4];
#pragma unroll
      for (int i = 0; i < 4; i++) af[i] = As4[(((wm * 4 + i) * 2 + kk) << 6) + lane];
#pragma unroll
      for (int j = 0; j < 4; j++) bw[j] = Ws4[(((wn * 4 + j) * 2 + kk) << 6) + lane];
#pragma unroll
      for (int i = 0; i < 4; i++)
#pragma unroll
        for (int j = 0; j < 4; j++)
          acc[i][j] = __builtin_amdgcn_mfma_f32_16x16x32_bf16(af[i], bw[j], acc[i][j], 0, 0, 0);
    }
    __syncthreads();
  }

#pragma unroll
  for (int i = 0; i < 4; i++) {
#pragma unroll
    for (int j = 0; j < 4; j++) {
#pragma unroll
      for (int r = 0; r < 4; r++) {
        int gr = m0 + wm * 64 + i * 16 + quad * 4 + r;
        int gc = n0 + wn * 64 + j * 16 + lr;
        size_t idx = (size_t)gr * N + gc;
        float v = acc[i][j][r];
        if constexpr (EPI == EPI_BF16_PART) {
          Cb[poff + idx] = f2bf(v);
        } else if constexpr (EPI == EPI_BF16_QKV) {
          Cb[idx] = f2bf(gc < 1024 ? v * 0.125f : v);
        } else {  // EPI_BF16_GELU
          v += bias[gc];
          float z = 0.7978845608028654f * (v + 0.044715f * v * v * v);
          float t = 2.f / (1.f + __expf(-2.f * z)) - 1.f;
          Cb[idx] = f2bf(0.5f * v * (1.f + t));
        }
      }
    }
  }
}

// ---------------- MFMA flash attention (causal), S^T formulation ----------
#define VTS 72
__device__ __forceinline__ void stage_k(const u16* Kbase, int ks, u16* kfbuf,
                                        int wave, int lr, int quad) {
#pragma unroll
  for (int p = 0; p < 2; ++p) {
    int q = wave * 2 + p;
    int key = ((q >> 1) << 4) + lr;
    int c8 = ((q & 1) << 2) + quad;
    GLOAD16(Kbase + (size_t)(ks + key) * 3072 + c8 * 8, (char*)kfbuf + q * 1024);
  }
}
__device__ __forceinline__ void load_v(const u16* Vbase, int ks, int vkey0, int vc8,
                                       ushort8v& va, ushort8v& vb) {
  va = *(const ushort8v*)(Vbase + (size_t)(ks + vkey0) * 3072 + vc8 * 8);
  vb = *(const ushort8v*)(Vbase + (size_t)(ks + vkey0 + 1) * 3072 + vc8 * 8);
}
__device__ __forceinline__ void write_vt(u16* vt, int vc8, int vcol,
                                         ushort8v va, ushort8v vb) {
#pragma unroll
  for (int j = 0; j < 8; ++j) {
    unsigned pk = (unsigned)va[j] | ((unsigned)vb[j] << 16);
    *(unsigned*)(vt + (size_t)(vc8 * 8 + j) * VTS + vcol) = pk;
  }
}

__global__ __launch_bounds__(256) void attn_kernel(const u16* __restrict__ qkv,
                                                   u16* __restrict__ ctx) {
  __shared__ u16 Kf[2][4096];        // 16 KB, fragment order
  __shared__ u16 Vt[2][64 * VTS];    // 18 KB, V^T swizzled
  int tid = threadIdx.x;
  int wave = tid >> 6, lane = tid & 63;
  int lr = lane & 15, quad = lane >> 4;
  int id = blockIdx.x;
  int bh = id & 31;
  int t = 31 - (id >> 5);            // LPT: longest q-tiles dispatch first
  int b = bh >> 4, h = bh & 15;
  int q0 = t * 64;
  const u16* qkvb = qkv + (size_t)(b * SEQL) * 3072;
  int qrow = q0 + wave * 16 + lr;
  const u16* Qp = qkvb + (size_t)qrow * 3072 + h * 64 + quad * 8;
  bf16x8v qf0 = *(const bf16x8v*)(Qp);        // Q pre-scaled by 0.125 in GEMM
  bf16x8v qf1 = *(const bf16x8v*)(Qp + 32);
  const u16* Kbase = qkvb + 1024 + h * 64;
  const u16* Vbase = qkvb + 2048 + h * 64;
  int vkey0 = (tid >> 3) * 2, vc8 = tid & 7;
  int vcol = vkey0 ^ (vc8 << 2);

  float m = -INFINITY, l = 0.f;
  f32x4v accO[4];
#pragma unroll
  for (int r = 0; r < 4; r++) {
    f32x4v z = {0.f, 0.f, 0.f, 0.f};
    accO[r] = z;
  }

  int nkt = t + 1;
  {
    stage_k(Kbase, 0, Kf[0], wave, lr, quad);
    ushort8v va, vb;
    load_v(Vbase, 0, vkey0, vc8, va, vb);
    write_vt(Vt[0], vc8, vcol, va, vb);
  }
  __syncthreads();

  for (int kt = 0; kt < nkt; ++kt) {
    int cur = kt & 1, nxt = cur ^ 1;
    ushort8v va, vb;
    bool pre = (kt + 1 < nkt);
    if (pre) {
      stage_k(Kbase, (kt + 1) * 64, Kf[nxt], wave, lr, quad);
      load_v(Vbase, (kt + 1) * 64, vkey0, vc8, va, vb);
    }
    const bf16x8v* Kc = (const bf16x8v*)Kf[cur];
    const u16* Vc = Vt[cur];
    // ---- S^T = K Q^T ----
    f32x4v accS[4];
#pragma unroll
    for (int jb = 0; jb < 4; jb++) {
      f32x4v z = {0.f, 0.f, 0.f, 0.f};
      accS[jb] = z;
    }
#pragma unroll
    for (int jb = 0; jb < 4; jb++) {
      accS[jb] = __builtin_amdgcn_mfma_f32_16x16x32_bf16(Kc[((jb * 2 + 0) << 6) + lane], qf0, accS[jb], 0, 0, 0);
      accS[jb] = __builtin_amdgcn_mfma_f32_16x16x32_bf16(Kc[((jb * 2 + 1) << 6) + lane], qf1, accS[jb], 0, 0, 0);
    }
    if (kt == t) {  // diagonal tile: mask key > q
#pragma unroll
      for (int jb = 0; jb < 4; jb++)
#pragma unroll
        for (int r = 0; r < 4; r++)
          if (jb * 16 + quad * 4 + r > wave * 16 + lr) accS[jb][r] = -INFINITY;
    }
    // ---- per-lane online softmax (q = lane&15) ----
    float smax = accS[0][0];
#pragma unroll
    for (int jb = 0; jb < 4; jb++)
#pragma unroll
      for (int r = 0; r < 4; r++) smax = fmaxf(smax, accS[jb][r]);
    smax = fmaxf(smax, __shfl_xor(smax, 16, 64));
    smax = fmaxf(smax, __shfl_xor(smax, 32, 64));
    float mn = fmaxf(m, smax);
    float alpha = __expf(m - mn);
    m = mn;
    float ps = 0.f;
#pragma unroll
    for (int jb = 0; jb < 4; jb++)
#pragma unroll
      for (int r = 0; r < 4; r++) {
        accS[jb][r] = __expf(accS[jb][r] - mn);
        ps += accS[jb][r];
      }
    ps += __shfl_xor(ps, 16, 64);
    ps += __shfl_xor(ps, 32, 64);
    l = l * alpha + ps;
    float ar[4];
#pragma unroll
    for (int r = 0; r < 4; r++) ar[r] = __shfl(alpha, quad * 4 + r, 16);
#pragma unroll
    for (int nb = 0; nb < 4; nb++)
#pragma unroll
      for (int r = 0; r < 4; r++) accO[nb][r] *= ar[r];
    // ---- O += P V ----
#pragma unroll
    for (int kk = 0; kk < 2; ++kk) {
      ushort8v pp;
#pragma unroll
      for (int j = 0; j < 4; ++j) {
        pp[j]     = f2bf_trunc(accS[2 * kk][j]);
        pp[j + 4] = f2bf_trunc(accS[2 * kk + 1][j]);
      }
      bf16x8v pav = __builtin_bit_cast(bf16x8v, pp);
#pragma unroll
      for (int nb = 0; nb < 4; nb++) {
        int dim = nb * 16 + lr;
        int f = (nb * 2 + (lr >> 3)) & 7;
        int col1 = (kk * 32 + quad * 4) ^ (f << 2);
        ushort4v v0 = *(const ushort4v*)(Vc + dim * VTS + col1);
        ushort4v v1 = *(const ushort4v*)(Vc + dim * VTS + (col1 ^ 16));
        ushort8v vv;
#pragma unroll
        for (int j = 0; j < 4; ++j) { vv[j] = v0[j]; vv[j + 4] = v1[j]; }
        accO[nb] = __builtin_amdgcn_mfma_f32_16x16x32_bf16(pav, __builtin_bit_cast(bf16x8v, vv), accO[nb], 0, 0, 0);
      }
    }
    if (pre) write_vt(Vt[nxt], vc8, vcol, va, vb);
    __syncthreads();  // single barrier per tile
  }
  float linv = 1.f / l;
  float rr[4];
#pragma unroll
  for (int r = 0; r < 4; r++) rr[r] = __shfl(linv, quad * 4 + r, 16);
#pragma unroll
  for (int nb = 0; nb < 4; nb++)
#pragma unroll
    for (int r = 0; r < 4; r++) {
      int rowg = q0 + wave * 16 + quad * 4 + r;
      ctx[(size_t)(b * SEQL + rowg) * D_EMBD + h * 64 + nb * 16 + lr] =
          f2bf(accO[nb][r] * rr[r]);
    }
}

extern "C" void kernel_launch(void* const* d_in, const int* in_sizes, int n_in,
                              void* d_out, int out_size, void* d_ws, size_t ws_size,
                              hipStream_t stream) {
  const float* x    = (const float*)d_in[0];
  const float* wq   = (const float*)d_in[1];
  const float* wk   = (const float*)d_in[2];
  const float* wv   = (const float*)d_in[3];
  const float* wo   = (const float*)d_in[4];
  const float* bo   = (const float*)d_in[5];
  const float* w1   = (const float*)d_in[6];
  const float* b1   = (const float*)d_in[7];
  const float* w2   = (const float*)d_in[8];
  const float* b2   = (const float*)d_in[9];
  const float* ln1s = (const float*)d_in[10];
  const float* ln1b = (const float*)d_in[11];
  const float* ln2s = (const float*)d_in[12];
  const float* ln2b = (const float*)d_in[13];
  float* out = (float*)d_out;

  char* base = (char*)d_ws;
  size_t off = 0;
  auto alloc = [&](size_t bytes) {
    char* r = base + off;
    off += (bytes + 255) & ~(size_t)255;
    return r;
  };
  u16*   wcat = (u16*)alloc((size_t)3072 * 1024 * 2);
  u16*   wob  = (u16*)alloc((size_t)1024 * 1024 * 2);
  u16*   w1b  = (u16*)alloc((size_t)4096 * 1024 * 2);
  u16*   w2b  = (u16*)alloc((size_t)1024 * 4096 * 2);
  u16*   xn   = (u16*)alloc((size_t)TOK * 1024 * 2);   // 8 MB
  u16*   qkv  = (u16*)alloc((size_t)TOK * 3072 * 2);   // 24 MB
  u16*   ctx  = (u16*)alloc((size_t)TOK * 1024 * 2);
  float* hbuf = (float*)alloc((size_t)TOK * 1024 * 4);
  u16*   ybuf = (u16*)alloc((size_t)TOK * 1024 * 2);
  u16*   gbuf = (u16*)alloc((size_t)TOK * 4096 * 2);
  // split-K bf16 partials (4 x 8 MB) overlay the dead xn+qkv region (32 MB):
  //   wo partials live attn->ln2f; w2 partials live w2gemm->reduce_w2.
  u16* woP = (u16*)xn;
  u16* w2P = (u16*)xn;

  // ALL weight conversions at t=0 (one launch; writebacks settle before use)
  cvt_all_kernel<<<12288, 256, 0, stream>>>(wq, wk, wv, wo, w1, w2,
                                            wcat, wob, w1b, w2b);
  ln_kernel<<<TOK, 256, 0, stream>>>(x, ln1s, ln1b, xn);
  gemm_nt<EPI_BF16_QKV><<<dim3(24, 32), 256, 0, stream>>>(
      xn, wcat, nullptr, qkv, nullptr, TOK, 3072, 1024);
  attn_kernel<<<1024, 256, 0, stream>>>(qkv, ctx);
  // wo: split-K=4 bf16 partials (qkv region now dead)
  gemm_nt<EPI_BF16_PART><<<dim3(8, 32, 4), 256, 0, stream>>>(
      ctx, wob, nullptr, woP, nullptr, TOK, 1024, 1024);
  // fused: h = x + sum(partials) + bo -> hbuf; ln2(h) -> ybuf
  ln2f_kernel<<<TOK, 256, 0, stream>>>(woP, x, bo, ln2s, ln2b, hbuf, ybuf);
  gemm_nt<EPI_BF16_GELU><<<dim3(32, 32), 256, 0, stream>>>(
      ybuf, w1b, nullptr, gbuf, b1, TOK, 4096, 1024);
  gemm_nt<EPI_BF16_PART><<<dim3(8, 32, 4), 256, 0, stream>>>(
      gbuf, w2b, nullptr, w2P, nullptr, TOK, 1024, 4096);
  reduce_w2_kernel<<<4096, 256, 0, stream>>>(w2P, hbuf, b2, out);
}